// Round 2
// baseline (1162.973 us; speedup 1.0000x reference)
//
#include <hip/hip_runtime.h>
#include <math.h>

#define NN 512
#define BB 8
#define CC 64
#define TT 64
#define LL 58
#define CL (CC*LL)        // 3712
#define BCL (BB*CC*LL)    // 29696
#define SZ ((size_t)NN*BCL)   // 15,204,352 elements per state

typedef _Float16 half8 __attribute__((ext_vector_type(8)));
typedef _Float16 half4 __attribute__((ext_vector_type(4)));
typedef float f32x4 __attribute__((ext_vector_type(4)));

// ---------------- adjacency normalization ----------------
__global__ __launch_bounds__(64) void prep_adj(const float* __restrict__ adj,
                                               float* __restrict__ dinv1,
                                               float* __restrict__ dinv2){
  int v = blockIdx.x;
  int lane = threadIdx.x;
  float rs = 0.f, cs = 0.f;
  for (int w = lane; w < NN; w += 64){
    rs += adj[v*NN + w];
    cs += adj[w*NN + v];
  }
  for (int off = 32; off > 0; off >>= 1){
    rs += __shfl_down(rs, off);
    cs += __shfl_down(cs, off);
  }
  if (lane == 0){
    dinv1[v] = 1.f / sqrtf(rs + 1.f);
    dinv2[v] = 1.f / sqrtf(cs + 1.f);
  }
}

__global__ __launch_bounds__(256) void build_norm(const float* __restrict__ adj,
                                                  const float* __restrict__ dinv1,
                                                  const float* __restrict__ dinv2,
                                                  _Float16* __restrict__ An,
                                                  _Float16* __restrict__ AnT){
  int v = blockIdx.x;
  float d1v = dinv1[v], d2v = dinv2[v];
  for (int w = threadIdx.x; w < NN; w += 256){
    float diag = (v == w) ? 1.f : 0.f;
    An[v*NN + w]  = (_Float16)(d1v * (adj[v*NN + w] + diag) * dinv1[w]);
    AnT[v*NN + w] = (_Float16)(d2v * (adj[w*NN + v] + diag) * dinv2[w]);
  }
}

// ---------------- W transpose+stage: W[o][320] fp32 -> Wt[sc][64] fp32 ----------------
__global__ __launch_bounds__(256) void wt_prep(const float* __restrict__ W1,
                                               const float* __restrict__ W2,
                                               float* __restrict__ Wt1,
                                               float* __restrict__ Wt2){
  int idx = blockIdx.x*256 + threadIdx.x;   // grid 80 -> 20480
  int o = idx / 320;
  int sc = idx - o*320;
  Wt1[sc*64 + o] = W1[idx];
  Wt2[sc*64 + o] = W2[idx];
}

// ---------------- gated inception conv (fp32 math, f16 out, n-major) ----------------
template<int K>
__device__ void conv_accum(const float* xs, const float* __restrict__ wf,
                           const float* __restrict__ wg,
                           int oc, int lgrp, float* accF, float* accG){
  for (int ic = 0; ic < CC; ++ic){
    float wrf[K], wrg[K];
    #pragma unroll
    for (int q = 0; q < K; ++q){
      wrf[q] = wf[(oc*CC + ic)*K + q];
      wrg[q] = wg[(oc*CC + ic)*K + q];
    }
    const float* xr = &xs[ic*TT + 7 - K + lgrp];
    #pragma unroll
    for (int i = 0; i < 15; ++i){
      #pragma unroll
      for (int q = 0; q < K; ++q){
        float xv = xr[4*i + q];
        accF[i] = fmaf(xv, wrf[q], accF[i]);
        accG[i] = fmaf(xv, wrg[q], accG[i]);
      }
    }
  }
}

__global__ __launch_bounds__(256) void inception(
    const float* __restrict__ x,
    const float* __restrict__ w10, const float* __restrict__ b10,
    const float* __restrict__ w11, const float* __restrict__ b11,
    const float* __restrict__ w12, const float* __restrict__ b12,
    const float* __restrict__ w13, const float* __restrict__ b13,
    const float* __restrict__ w20, const float* __restrict__ b20,
    const float* __restrict__ w21, const float* __restrict__ b21,
    const float* __restrict__ w22, const float* __restrict__ b22,
    const float* __restrict__ w23, const float* __restrict__ b23,
    _Float16* __restrict__ h_nm){
  __shared__ float xs[CC*TT + 8];
  int n = blockIdx.x >> 3;
  int b = blockIdx.x & 7;
  int t = threadIdx.x;
  const float* xb = x + (size_t)b*CC*NN*TT + (size_t)n*TT;
  float4* xs4 = (float4*)xs;
  #pragma unroll
  for (int r = 0; r < 4; ++r){
    int f = t + r*256;
    int ic = f >> 4, tq = f & 15;
    xs4[f] = *(const float4*)(xb + (size_t)ic*NN*TT + tq*4);
  }
  __syncthreads();

  int j = t >> 6;
  int lane = t & 63;
  int oc = lane & 15;
  int lgrp = lane >> 4;
  const float* wf  = (j==0)?w10:(j==1)?w11:(j==2)?w12:w13;
  const float* wg  = (j==0)?w20:(j==1)?w21:(j==2)?w22:w23;
  const float* bfp = (j==0)?b10:(j==1)?b11:(j==2)?b12:b13;
  const float* bgp = (j==0)?b20:(j==1)?b21:(j==2)?b22:b23;

  float accF[15], accG[15];
  #pragma unroll
  for (int i = 0; i < 15; ++i){ accF[i] = 0.f; accG[i] = 0.f; }

  if      (j == 0) conv_accum<2>(xs, wf, wg, oc, lgrp, accF, accG);
  else if (j == 1) conv_accum<3>(xs, wf, wg, oc, lgrp, accF, accG);
  else if (j == 2) conv_accum<6>(xs, wf, wg, oc, lgrp, accF, accG);
  else             conv_accum<7>(xs, wf, wg, oc, lgrp, accF, accG);

  float bf = bfp[oc], bg = bgp[oc];
  int c = j*16 + oc;
  _Float16* hb = h_nm + (size_t)n*BCL + (size_t)b*CL + (size_t)c*LL;
  #pragma unroll
  for (int i = 0; i < 15; ++i){
    int l = lgrp + 4*i;
    if (l < LL){
      float fv = tanhf(accF[i] + bf);
      float gv = 1.f / (1.f + expf(-(accG[i] + bg)));
      hb[l] = (_Float16)(fv * gv);
    }
  }
}

// ---------------- transpose h_nm[v][m] -> S_h[m][v] (f16) ----------------
__global__ __launch_bounds__(256) void transpose_h(const _Float16* __restrict__ h_nm,
                                                   _Float16* __restrict__ S_h){
  __shared__ _Float16 T[64][72];
  int m0 = blockIdx.x * 64;
  int v0 = blockIdx.y * 64;
  int t = threadIdx.x;
  #pragma unroll
  for (int i = 0; i < 2; ++i){
    int c = t + i*256;            // 0..511 chunks of 8
    int r = c >> 3, sg = c & 7;
    *(half8*)&T[r][sg*8] = *(const half8*)&h_nm[(size_t)(v0 + r)*BCL + m0 + sg*8];
  }
  __syncthreads();
  #pragma unroll
  for (int i = 0; i < 2; ++i){
    int c = t + i*256;
    int mr = c >> 3, sg = c & 7;  // mr = m-local row, sg = v-octet
    half8 hv;
    #pragma unroll
    for (int q = 0; q < 8; ++q) hv[q] = T[sg*8 + q][mr];
    *(half8*)&S_h[(size_t)(m0 + mr)*NN + v0 + sg*8] = hv;
  }
}

// ---------------- f-eval: O[m][v] = epi( G = An * S_in^T ) -------------
// MODE 0: O = G/3 + (2/3) Bst              (y2; Bst=h)
// MODE 1: O = G - 2 Bst + 2 P1             (y3: Bst=y2,P1=h | y4: Bst=y3,P1=y2)
// MODE 3: O = .125G + .25Bst + .75P1 - .125P2   (yf: Bst=y4,P1=y3,P2=h)
template<int MODE>
__global__ __launch_bounds__(256) void gemm_eval(
    const _Float16* __restrict__ A,    // [512][512] row v, col w
    const _Float16* __restrict__ Bst,  // state [m][w]
    const _Float16* __restrict__ P1,
    const _Float16* __restrict__ P2,
    _Float16* __restrict__ O){
  __shared__ _Float16 Ash[256][40];
  __shared__ _Float16 Bsh[64][40];
  int t = threadIdx.x;
  int m0 = blockIdx.x * 64;
  int v0 = blockIdx.y * 256;
  int w = t >> 6;            // wave -> v-subblock of 64
  int lane = t & 63;
  int lr = lane & 15;
  int koff = (lane >> 4) * 8;

  f32x4 acc[4][4] = {};

  for (int k0 = 0; k0 < NN; k0 += 32){
    // global loads (before barrier for overlap)
    half8 areg[4];
    #pragma unroll
    for (int i = 0; i < 4; ++i){
      int c = t + i*256;           // 0..1023
      int r = c >> 2, sg = c & 3;
      areg[i] = *(const half8*)&A[(size_t)(v0 + r)*NN + k0 + sg*8];
    }
    int br = t >> 2, bsg = t & 3;
    half8 breg = *(const half8*)&Bst[(size_t)(m0 + br)*NN + k0 + bsg*8];

    __syncthreads();
    #pragma unroll
    for (int i = 0; i < 4; ++i){
      int c = t + i*256;
      int r = c >> 2, sg = c & 3;
      *(half8*)&Ash[r][sg*8] = areg[i];
    }
    *(half8*)&Bsh[br][bsg*8] = breg;
    __syncthreads();

    half8 af[4], bf[4];
    #pragma unroll
    for (int i = 0; i < 4; ++i) af[i] = *(half8*)&Ash[w*64 + i*16 + lr][koff];
    #pragma unroll
    for (int jj = 0; jj < 4; ++jj) bf[jj] = *(half8*)&Bsh[jj*16 + lr][koff];
    #pragma unroll
    for (int i = 0; i < 4; ++i)
      #pragma unroll
      for (int jj = 0; jj < 4; ++jj)
        acc[i][jj] = __builtin_amdgcn_mfma_f32_16x16x32_f16(af[i], bf[jj], acc[i][jj], 0, 0, 0);
  }

  int q = lane >> 4;
  #pragma unroll
  for (int i = 0; i < 4; ++i){
    #pragma unroll
    for (int jj = 0; jj < 4; ++jj){
      int vv = v0 + w*64 + i*16 + q*4;
      int mq = m0 + jj*16 + lr;
      size_t base = (size_t)mq*NN + vv;
      half4 bq = *(const half4*)(Bst + base);
      half4 p1q = {}, p2q = {};
      if (MODE >= 1) p1q = *(const half4*)(P1 + base);
      if (MODE == 3) p2q = *(const half4*)(P2 + base);
      half4 oq;
      #pragma unroll
      for (int rr = 0; rr < 4; ++rr){
        float G = acc[i][jj][rr];
        float bv = (float)bq[rr];
        float val;
        if (MODE == 0)      val = (1.f/3.f)*G + (2.f/3.f)*bv;
        else if (MODE == 1) val = G - 2.f*bv + 2.f*(float)p1q[rr];
        else                val = 0.125f*G + 0.25f*bv + 0.75f*(float)p1q[rr] - 0.125f*(float)p2q[rr];
        oq[rr] = (_Float16)val;
      }
      *(half4*)(O + base) = oq;
    }
  }
}

// ---------------- 1x1 mix (VALU, uniform-W scalar loads) ----------------
// tmp[(b*58+l)*64 + o][v] (f16) = sum_s,c Wt[s*64+c][o] * S_s[(b,c,l)][v] + bias
template<int PASS>
__global__ __launch_bounds__(256) void combine(
    const _Float16* __restrict__ Sh, const _Float16* __restrict__ S2,
    const _Float16* __restrict__ S3, const _Float16* __restrict__ S4,
    const _Float16* __restrict__ Sf, const float* __restrict__ Wt,
    const float* __restrict__ bias, _Float16* __restrict__ tmp){
  int l = blockIdx.x;      // 58
  int b = blockIdx.y;      // 8
  int oh = blockIdx.z * 32;
  int t = threadIdx.x;     // v = t, t+256

  float acc0[32], acc1[32];
  #pragma unroll
  for (int oo = 0; oo < 32; ++oo){ acc0[oo] = 0.f; acc1[oo] = 0.f; }

  const _Float16* Sarr[5] = {Sh, S2, S3, S4, Sf};
  for (int s = 0; s < 5; ++s){
    const _Float16* Sb = Sarr[s] + (size_t)(b*CL + l)*NN;
    for (int c = 0; c < CC; ++c){
      const _Float16* row = Sb + (size_t)c*LL*NN;
      float s0 = (float)row[t];
      float s1 = (float)row[t + 256];
      const float* wrow = Wt + (s*64 + c)*64 + oh;   // uniform -> s_load
      #pragma unroll
      for (int oo = 0; oo < 32; ++oo){
        float wv = wrow[oo];
        acc0[oo] = fmaf(wv, s0, acc0[oo]);
        acc1[oo] = fmaf(wv, s1, acc1[oo]);
      }
    }
  }
  size_t ob = ((size_t)(b*58 + l)*64 + oh)*NN;
  #pragma unroll
  for (int oo = 0; oo < 32; ++oo){
    float bv = bias[oh + oo];
    size_t i0 = ob + (size_t)oo*NN + t;
    if (PASS == 0){
      tmp[i0]       = (_Float16)(acc0[oo] + bv);
      tmp[i0 + 256] = (_Float16)(acc1[oo] + bv);
    } else {
      tmp[i0]       = (_Float16)((float)tmp[i0]       + acc0[oo] + bv);
      tmp[i0 + 256] = (_Float16)((float)tmp[i0 + 256] + acc1[oo] + bv);
    }
  }
}

// ---------------- untranspose tmp[(b,l)][o][v] -> out[b][o][v][6+l], zero pad ----------------
__global__ __launch_bounds__(256) void untranspose(const _Float16* __restrict__ tmp,
                                                   float* __restrict__ out){
  __shared__ float T[58][65];
  int o = blockIdx.x;          // 64
  int b = blockIdx.y;          // 8
  int v0 = blockIdx.z * 64;    // 8
  int t = threadIdx.x;
  for (int idx = t; idx < 58*64; idx += 256){
    int lr = idx >> 6, vv = idx & 63;
    T[lr][vv] = (float)tmp[((size_t)(b*58 + lr)*64 + o)*NN + v0 + vv];
  }
  __syncthreads();
  #pragma unroll
  for (int i = 0; i < 16; ++i){
    int c = t + i*256;           // 0..4095
    int vv = c >> 6, tt = c & 63;
    float val = (tt < 6) ? 0.f : T[tt - 6][vv];
    out[((size_t)(b*64 + o)*NN + v0 + vv)*TT + tt] = val;
  }
}

// ---------------- launch ----------------
extern "C" void kernel_launch(void* const* d_in, const int* in_sizes, int n_in,
                              void* d_out, int out_size, void* d_ws, size_t ws_size,
                              hipStream_t stream){
  const float* x   = (const float*)d_in[0];
  const float* adj = (const float*)d_in[1];
  const float* w1[4] = {(const float*)d_in[2],  (const float*)d_in[4],
                        (const float*)d_in[6],  (const float*)d_in[8]};
  const float* b1[4] = {(const float*)d_in[3],  (const float*)d_in[5],
                        (const float*)d_in[7],  (const float*)d_in[9]};
  const float* w2[4] = {(const float*)d_in[10], (const float*)d_in[12],
                        (const float*)d_in[14], (const float*)d_in[16]};
  const float* b2[4] = {(const float*)d_in[11], (const float*)d_in[13],
                        (const float*)d_in[15], (const float*)d_in[17]};
  const float* m1w = (const float*)d_in[18];
  const float* m1b = (const float*)d_in[19];
  const float* m2w = (const float*)d_in[20];
  const float* m2b = (const float*)d_in[21];

  // workspace layout (bytes) — total ~184 MB
  char* wsb = (char*)d_ws;
  float* dinv1 = (float*)(wsb);                    // 2 KB
  float* dinv2 = (float*)(wsb + 2048);             // 2 KB
  float* Wt1   = (float*)(wsb + 4096);             // 80 KB
  float* Wt2   = (float*)(wsb + 4096 + 81920);     // 80 KB
  _Float16* An  = (_Float16*)(wsb + 167936);       // 512 KB
  _Float16* AnT = (_Float16*)(wsb + 167936 + 524288);
  size_t sbytes = SZ * 2;                          // 30,408,704
  char* sbase = wsb + 1216512;
  _Float16* S_h = (_Float16*)(sbase);
  _Float16* S2  = (_Float16*)(sbase + sbytes);
  _Float16* S3  = (_Float16*)(sbase + 2*sbytes);
  _Float16* S4  = (_Float16*)(sbase + 3*sbytes);
  _Float16* S5  = (_Float16*)(sbase + 4*sbytes);
  _Float16* tmp = (_Float16*)(sbase + 5*sbytes);   // also h_nm scratch (dead before combine)
  _Float16* h_nm = tmp;
  float* out = (float*)d_out;

  prep_adj<<<NN, 64, 0, stream>>>(adj, dinv1, dinv2);
  build_norm<<<NN, 256, 0, stream>>>(adj, dinv1, dinv2, An, AnT);
  wt_prep<<<80, 256, 0, stream>>>(m1w, m2w, Wt1, Wt2);
  inception<<<BB*NN, 256, 0, stream>>>(x,
      w1[0],b1[0],w1[1],b1[1],w1[2],b1[2],w1[3],b1[3],
      w2[0],b2[0],w2[1],b2[1],w2[2],b2[2],w2[3],b2[3], h_nm);
  transpose_h<<<dim3(BCL/64, NN/64), 256, 0, stream>>>(h_nm, S_h);

  dim3 gg(BCL/64, 2);
  for (int pass = 0; pass < 2; ++pass){
    const _Float16* A = pass ? AnT : An;
    gemm_eval<0><<<gg, 256, 0, stream>>>(A, S_h, nullptr, nullptr, S2);
    gemm_eval<1><<<gg, 256, 0, stream>>>(A, S2, S_h, nullptr, S3);
    gemm_eval<1><<<gg, 256, 0, stream>>>(A, S3, S2, nullptr, S4);
    gemm_eval<3><<<gg, 256, 0, stream>>>(A, S4, S3, S_h, S5);
    if (pass == 0)
      combine<0><<<dim3(58, 8, 2), 256, 0, stream>>>(S_h, S2, S3, S4, S5, Wt1, m1b, tmp);
    else
      combine<1><<<dim3(58, 8, 2), 256, 0, stream>>>(S_h, S2, S3, S4, S5, Wt2, m2b, tmp);
  }
  untranspose<<<dim3(64, 8, 8), 256, 0, stream>>>(tmp, out);
}

// Round 3
// 876.982 us; speedup vs baseline: 1.3261x; 1.3261x over previous
//
#include <hip/hip_runtime.h>
#include <math.h>

#define NN 512
#define BB 8
#define CC 64
#define TT 64
#define LL 58
#define CL (CC*LL)        // 3712
#define BCL (BB*CC*LL)    // 29696
#define SZ ((size_t)NN*BCL)   // 15,204,352 elements per state

typedef _Float16 half8 __attribute__((ext_vector_type(8)));
typedef _Float16 half4 __attribute__((ext_vector_type(4)));
typedef float f32x4 __attribute__((ext_vector_type(4)));

// ---------------- adjacency normalization ----------------
__global__ __launch_bounds__(64) void prep_adj(const float* __restrict__ adj,
                                               float* __restrict__ dinv1,
                                               float* __restrict__ dinv2){
  int v = blockIdx.x;
  int lane = threadIdx.x;
  float rs = 0.f, cs = 0.f;
  for (int w = lane; w < NN; w += 64){
    rs += adj[v*NN + w];
    cs += adj[w*NN + v];
  }
  for (int off = 32; off > 0; off >>= 1){
    rs += __shfl_down(rs, off);
    cs += __shfl_down(cs, off);
  }
  if (lane == 0){
    dinv1[v] = 1.f / sqrtf(rs + 1.f);
    dinv2[v] = 1.f / sqrtf(cs + 1.f);
  }
}

__global__ __launch_bounds__(256) void build_norm(const float* __restrict__ adj,
                                                  const float* __restrict__ dinv1,
                                                  const float* __restrict__ dinv2,
                                                  _Float16* __restrict__ An,
                                                  _Float16* __restrict__ AnT){
  int v = blockIdx.x;
  float d1v = dinv1[v], d2v = dinv2[v];
  for (int w = threadIdx.x; w < NN; w += 256){
    float diag = (v == w) ? 1.f : 0.f;
    An[v*NN + w]  = (_Float16)(d1v * (adj[v*NN + w] + diag) * dinv1[w]);
    AnT[v*NN + w] = (_Float16)(d2v * (adj[w*NN + v] + diag) * dinv2[w]);
  }
}

// ---------------- W transpose+stage: W[o][320] fp32 -> Wt[sc][64] fp32 ----------------
__global__ __launch_bounds__(256) void wt_prep(const float* __restrict__ W1,
                                               const float* __restrict__ W2,
                                               float* __restrict__ Wt1,
                                               float* __restrict__ Wt2){
  int idx = blockIdx.x*256 + threadIdx.x;   // grid 80 -> 20480
  int o = idx / 320;
  int sc = idx - o*320;
  Wt1[sc*64 + o] = W1[idx];
  Wt2[sc*64 + o] = W2[idx];
}

// ---------------- inception weight prep ----------------
// WfG[128 rows][448 k], k = q'*64 + ic; row<64: filt c=row, else gate c=row-64.
// branch j = (row&63)>>4, oc = row&15, kj={2,3,6,7}; valid q' >= 7-kj.
__global__ __launch_bounds__(448) void wfg_prep(
    const float* __restrict__ w10, const float* __restrict__ w11,
    const float* __restrict__ w12, const float* __restrict__ w13,
    const float* __restrict__ w20, const float* __restrict__ w21,
    const float* __restrict__ w22, const float* __restrict__ w23,
    const float* __restrict__ b10, const float* __restrict__ b11,
    const float* __restrict__ b12, const float* __restrict__ b13,
    const float* __restrict__ b20, const float* __restrict__ b21,
    const float* __restrict__ b22, const float* __restrict__ b23,
    _Float16* __restrict__ WfG, float* __restrict__ biasFG){
  int r = blockIdx.x;         // 0..127
  int t = threadIdx.x;        // 0..447
  int qp = t >> 6, ic = t & 63;
  int gate = r >> 6;
  int j = (r >> 4) & 3;
  int oc = r & 15;
  const int kjs[4] = {2, 3, 6, 7};
  int kj = kjs[j];
  const float* wsel = gate ? ((j==0)?w20:(j==1)?w21:(j==2)?w22:w23)
                           : ((j==0)?w10:(j==1)?w11:(j==2)?w12:w13);
  int off = 7 - kj;
  float val = (qp >= off) ? wsel[(oc*64 + ic)*kj + (qp - off)] : 0.f;
  WfG[(size_t)r*448 + t] = (_Float16)val;
  if (t == 0){
    const float* bsel = gate ? ((j==0)?b20:(j==1)?b21:(j==2)?b22:b23)
                             : ((j==0)?b10:(j==1)?b11:(j==2)?b12:b13);
    biasFG[r] = bsel[oc];
  }
}

// ---------------- x transpose: x[b][ic][n][t] f32 -> xTg[b][t][n][ic] f16 ----------------
__global__ __launch_bounds__(256) void xt_prep(const float* __restrict__ x,
                                               _Float16* __restrict__ xTg){
  __shared__ float T[64][65];
  int n = blockIdx.x;   // 512
  int b = blockIdx.y;   // 8
  int tid = threadIdx.x;
  #pragma unroll
  for (int r = 0; r < 4; ++r){
    int f = tid + r*256;       // 0..1023
    int ic = f >> 4, t4 = f & 15;
    float4 v = *(const float4*)&x[(((size_t)(b*64 + ic))*512 + n)*64 + t4*4];
    T[ic][t4*4+0] = v.x; T[ic][t4*4+1] = v.y;
    T[ic][t4*4+2] = v.z; T[ic][t4*4+3] = v.w;
  }
  __syncthreads();
  #pragma unroll
  for (int r = 0; r < 2; ++r){
    int f = tid + r*256;       // 0..511
    int t = f >> 3, ch = f & 7;
    half8 hv;
    #pragma unroll
    for (int q2 = 0; q2 < 8; ++q2) hv[q2] = (_Float16)T[ch*8 + q2][t];
    *(half8*)&xTg[(((size_t)(b*64 + t))*512 + n)*64 + ch*8] = hv;
  }
}

// ---------------- inception via MFMA ----------------
// Block: (n-tile 32, l-tile 8, b). GEMM M=128 (64F+64G), K=448, cols = 8l x 32n.
// LDS X[t=14][n=32][ic=64] f16, 16B-chunk xor-swizzled by n&7. 57344 B.
// Wave w owns F rows w*16..+15 and G rows 64+w*16..+15; weights in registers.
__global__ __launch_bounds__(256) void inception_mfma(
    const _Float16* __restrict__ xTg,   // [b][t][n][ic]
    const _Float16* __restrict__ WfG,   // [128][448]
    const float* __restrict__ biasFG,   // [128]
    _Float16* __restrict__ S_h){
  __shared__ _Float16 X[14*32*64];      // indexed in 8-half chunks
  int nt = blockIdx.x;   // 0..15
  int lt = blockIdx.y;   // 0..7
  int b  = blockIdx.z;   // 0..7
  int n0 = nt*32, l0 = lt*8;
  int tid = threadIdx.x;

  // stage: 14 t-rows, each 32 n x 8 chunks = 256 half8 per row
  int sch = tid & 7, sn = (tid >> 3) & 31;
  #pragma unroll
  for (int r = 0; r < 14; ++r){
    int t = l0 + r;
    half8 v = {};
    if (t < 64)
      v = *(const half8*)&xTg[(((size_t)(b*64 + t))*512 + n0 + sn)*64 + sch*8];
    *(half8*)&X[(size_t)(r*256 + sn*8 + (sch ^ (sn & 7)))*8] = v;
  }

  int w = tid >> 6, lane = tid & 63;
  int m = lane & 15, kg = lane >> 4;

  // register-resident weights: 14 k-steps x (F,G)
  half8 wF[14], wG[14];
  const _Float16* wb = WfG + (size_t)(w*16 + m)*448 + kg*8;
  #pragma unroll
  for (int s = 0; s < 14; ++s){
    wF[s] = *(const half8*)(wb + s*32);
    wG[s] = *(const half8*)(wb + (size_t)64*448 + s*32);
  }
  f32x4 bF = *(const f32x4*)&biasFG[w*16 + kg*4];
  f32x4 bG = *(const f32x4*)&biasFG[64 + w*16 + kg*4];

  __syncthreads();

  for (int ll = 0; ll < 8; ++ll){
    f32x4 aF0 = {}, aF1 = {}, aG0 = {}, aG1 = {};
    #pragma unroll
    for (int s = 0; s < 14; ++s){
      int t = ll + (s >> 1);
      int c0 = (s & 1)*4 + kg;
      half8 b0 = *(half8*)&X[(size_t)(t*256 + m*8        + (c0 ^ (m & 7)))*8];
      half8 b1 = *(half8*)&X[(size_t)(t*256 + (16+m)*8   + (c0 ^ (m & 7)))*8];
      aF0 = __builtin_amdgcn_mfma_f32_16x16x32_f16(wF[s], b0, aF0, 0, 0, 0);
      aG0 = __builtin_amdgcn_mfma_f32_16x16x32_f16(wG[s], b0, aG0, 0, 0, 0);
      aF1 = __builtin_amdgcn_mfma_f32_16x16x32_f16(wF[s], b1, aF1, 0, 0, 0);
      aG1 = __builtin_amdgcn_mfma_f32_16x16x32_f16(wG[s], b1, aG1, 0, 0, 0);
    }
    int l = l0 + ll;
    if (l < LL){
      #pragma unroll
      for (int rr = 0; rr < 4; ++rr){
        int c = w*16 + kg*4 + rr;
        float F0 = aF0[rr] + bF[rr];
        float G0 = aG0[rr] + bG[rr];
        float F1 = aF1[rr] + bF[rr];
        float G1 = aG1[rr] + bG[rr];
        float h0 = tanhf(F0) * (1.f / (1.f + expf(-G0)));
        float h1 = tanhf(F1) * (1.f / (1.f + expf(-G1)));
        size_t base = ((size_t)(b*64 + c)*LL + l)*NN + n0;
        S_h[base + m]      = (_Float16)h0;
        S_h[base + 16 + m] = (_Float16)h1;
      }
    }
  }
}

// ---------------- f-eval: O[m][v] = epi( G = An * S_in^T ) -------------
// MODE 0: O = G/3 + (2/3) Bst              (y2; Bst=h)
// MODE 1: O = G - 2 Bst + 2 P1             (y3: Bst=y2,P1=h | y4: Bst=y3,P1=y2)
// MODE 3: O = .125G + .25Bst + .75P1 - .125P2   (yf: Bst=y4,P1=y3,P2=h)
template<int MODE>
__global__ __launch_bounds__(256) void gemm_eval(
    const _Float16* __restrict__ A,    // [512][512] row v, col w
    const _Float16* __restrict__ Bst,  // state [m][w]
    const _Float16* __restrict__ P1,
    const _Float16* __restrict__ P2,
    _Float16* __restrict__ O){
  __shared__ _Float16 Ash[256][40];
  __shared__ _Float16 Bsh[64][40];
  int t = threadIdx.x;
  int m0 = blockIdx.x * 64;
  int v0 = blockIdx.y * 256;
  int w = t >> 6;            // wave -> v-subblock of 64
  int lane = t & 63;
  int lr = lane & 15;
  int koff = (lane >> 4) * 8;

  f32x4 acc[4][4] = {};

  for (int k0 = 0; k0 < NN; k0 += 32){
    half8 areg[4];
    #pragma unroll
    for (int i = 0; i < 4; ++i){
      int c = t + i*256;
      int r = c >> 2, sg = c & 3;
      areg[i] = *(const half8*)&A[(size_t)(v0 + r)*NN + k0 + sg*8];
    }
    int br = t >> 2, bsg = t & 3;
    half8 breg = *(const half8*)&Bst[(size_t)(m0 + br)*NN + k0 + bsg*8];

    __syncthreads();
    #pragma unroll
    for (int i = 0; i < 4; ++i){
      int c = t + i*256;
      int r = c >> 2, sg = c & 3;
      *(half8*)&Ash[r][sg*8] = areg[i];
    }
    *(half8*)&Bsh[br][bsg*8] = breg;
    __syncthreads();

    half8 af[4], bf[4];
    #pragma unroll
    for (int i = 0; i < 4; ++i) af[i] = *(half8*)&Ash[w*64 + i*16 + lr][koff];
    #pragma unroll
    for (int jj = 0; jj < 4; ++jj) bf[jj] = *(half8*)&Bsh[jj*16 + lr][koff];
    #pragma unroll
    for (int i = 0; i < 4; ++i)
      #pragma unroll
      for (int jj = 0; jj < 4; ++jj)
        acc[i][jj] = __builtin_amdgcn_mfma_f32_16x16x32_f16(af[i], bf[jj], acc[i][jj], 0, 0, 0);
  }

  int q = lane >> 4;
  #pragma unroll
  for (int i = 0; i < 4; ++i){
    #pragma unroll
    for (int jj = 0; jj < 4; ++jj){
      int vv = v0 + w*64 + i*16 + q*4;
      int mq = m0 + jj*16 + lr;
      size_t base = (size_t)mq*NN + vv;
      half4 bq = *(const half4*)(Bst + base);
      half4 p1q = {}, p2q = {};
      if (MODE >= 1) p1q = *(const half4*)(P1 + base);
      if (MODE == 3) p2q = *(const half4*)(P2 + base);
      half4 oq;
      #pragma unroll
      for (int rr = 0; rr < 4; ++rr){
        float G = acc[i][jj][rr];
        float bv = (float)bq[rr];
        float val;
        if (MODE == 0)      val = (1.f/3.f)*G + (2.f/3.f)*bv;
        else if (MODE == 1) val = G - 2.f*bv + 2.f*(float)p1q[rr];
        else                val = 0.125f*G + 0.25f*bv + 0.75f*(float)p1q[rr] - 0.125f*(float)p2q[rr];
        oq[rr] = (_Float16)val;
      }
      *(half4*)(O + base) = oq;
    }
  }
}

// ---------------- 1x1 mix (VALU, uniform-W scalar loads) ----------------
template<int PASS>
__global__ __launch_bounds__(256) void combine(
    const _Float16* __restrict__ Sh, const _Float16* __restrict__ S2,
    const _Float16* __restrict__ S3, const _Float16* __restrict__ S4,
    const _Float16* __restrict__ Sf, const float* __restrict__ Wt,
    const float* __restrict__ bias, _Float16* __restrict__ tmp){
  int l = blockIdx.x;      // 58
  int b = blockIdx.y;      // 8
  int oh = blockIdx.z * 32;
  int t = threadIdx.x;     // v = t, t+256

  float acc0[32], acc1[32];
  #pragma unroll
  for (int oo = 0; oo < 32; ++oo){ acc0[oo] = 0.f; acc1[oo] = 0.f; }

  const _Float16* Sarr[5] = {Sh, S2, S3, S4, Sf};
  for (int s = 0; s < 5; ++s){
    const _Float16* Sb = Sarr[s] + (size_t)(b*CL + l)*NN;
    for (int c = 0; c < CC; ++c){
      const _Float16* row = Sb + (size_t)c*LL*NN;
      float s0 = (float)row[t];
      float s1 = (float)row[t + 256];
      const float* wrow = Wt + (s*64 + c)*64 + oh;   // uniform -> s_load
      #pragma unroll
      for (int oo = 0; oo < 32; ++oo){
        float wv = wrow[oo];
        acc0[oo] = fmaf(wv, s0, acc0[oo]);
        acc1[oo] = fmaf(wv, s1, acc1[oo]);
      }
    }
  }
  size_t ob = ((size_t)(b*58 + l)*64 + oh)*NN;
  #pragma unroll
  for (int oo = 0; oo < 32; ++oo){
    float bv = bias[oh + oo];
    size_t i0 = ob + (size_t)oo*NN + t;
    if (PASS == 0){
      tmp[i0]       = (_Float16)(acc0[oo] + bv);
      tmp[i0 + 256] = (_Float16)(acc1[oo] + bv);
    } else {
      tmp[i0]       = (_Float16)((float)tmp[i0]       + acc0[oo] + bv);
      tmp[i0 + 256] = (_Float16)((float)tmp[i0 + 256] + acc1[oo] + bv);
    }
  }
}

// ---------------- untranspose tmp[(b,l)][o][v] -> out[b][o][v][6+l], zero pad ----------------
__global__ __launch_bounds__(256) void untranspose(const _Float16* __restrict__ tmp,
                                                   float* __restrict__ out){
  __shared__ float T[58][65];
  int o = blockIdx.x;          // 64
  int b = blockIdx.y;          // 8
  int v0 = blockIdx.z * 64;    // 8
  int t = threadIdx.x;
  for (int idx = t; idx < 58*64; idx += 256){
    int lr = idx >> 6, vv = idx & 63;
    T[lr][vv] = (float)tmp[((size_t)(b*58 + lr)*64 + o)*NN + v0 + vv];
  }
  __syncthreads();
  #pragma unroll
  for (int i = 0; i < 16; ++i){
    int c = t + i*256;           // 0..4095
    int vv = c >> 6, tt = c & 63;
    float val = (tt < 6) ? 0.f : T[tt - 6][vv];
    out[((size_t)(b*64 + o)*NN + v0 + vv)*TT + tt] = val;
  }
}

// ---------------- launch ----------------
extern "C" void kernel_launch(void* const* d_in, const int* in_sizes, int n_in,
                              void* d_out, int out_size, void* d_ws, size_t ws_size,
                              hipStream_t stream){
  const float* x   = (const float*)d_in[0];
  const float* adj = (const float*)d_in[1];
  const float* w1[4] = {(const float*)d_in[2],  (const float*)d_in[4],
                        (const float*)d_in[6],  (const float*)d_in[8]};
  const float* b1[4] = {(const float*)d_in[3],  (const float*)d_in[5],
                        (const float*)d_in[7],  (const float*)d_in[9]};
  const float* w2[4] = {(const float*)d_in[10], (const float*)d_in[12],
                        (const float*)d_in[14], (const float*)d_in[16]};
  const float* b2[4] = {(const float*)d_in[11], (const float*)d_in[13],
                        (const float*)d_in[15], (const float*)d_in[17]};
  const float* m1w = (const float*)d_in[18];
  const float* m1b = (const float*)d_in[19];
  const float* m2w = (const float*)d_in[20];
  const float* m2b = (const float*)d_in[21];

  // workspace layout (bytes) — total ~184 MB
  char* wsb = (char*)d_ws;
  float* dinv1 = (float*)(wsb);
  float* dinv2 = (float*)(wsb + 2048);
  float* Wt1   = (float*)(wsb + 4096);
  float* Wt2   = (float*)(wsb + 4096 + 81920);
  _Float16* An  = (_Float16*)(wsb + 167936);
  _Float16* AnT = (_Float16*)(wsb + 167936 + 524288);
  size_t sbytes = SZ * 2;
  char* sbase = wsb + 1216512;
  _Float16* S_h = (_Float16*)(sbase);
  _Float16* S2  = (_Float16*)(sbase + sbytes);
  _Float16* S3  = (_Float16*)(sbase + 2*sbytes);
  _Float16* S4  = (_Float16*)(sbase + 3*sbytes);
  _Float16* S5  = (_Float16*)(sbase + 4*sbytes);
  _Float16* tmp = (_Float16*)(sbase + 5*sbytes);
  // xTg (33.6 MB) lives in S2+S3 slots: dead before gemm_eval<0> writes S2.
  _Float16* xTg = S2;
  _Float16* WfG = (_Float16*)(sbase + 6*sbytes);        // 114688 B
  float* biasFG = (float*)(sbase + 6*sbytes + 114688);  // 512 B
  float* out = (float*)d_out;

  prep_adj<<<NN, 64, 0, stream>>>(adj, dinv1, dinv2);
  build_norm<<<NN, 256, 0, stream>>>(adj, dinv1, dinv2, An, AnT);
  wt_prep<<<80, 256, 0, stream>>>(m1w, m2w, Wt1, Wt2);
  wfg_prep<<<128, 448, 0, stream>>>(
      w1[0],w1[1],w1[2],w1[3], w2[0],w2[1],w2[2],w2[3],
      b1[0],b1[1],b1[2],b1[3], b2[0],b2[1],b2[2],b2[3], WfG, biasFG);
  xt_prep<<<dim3(NN, BB), 256, 0, stream>>>(x, xTg);
  inception_mfma<<<dim3(16, 8, 8), 256, 0, stream>>>(xTg, WfG, biasFG, S_h);

  dim3 gg(BCL/64, 2);
  for (int pass = 0; pass < 2; ++pass){
    const _Float16* A = pass ? AnT : An;
    gemm_eval<0><<<gg, 256, 0, stream>>>(A, S_h, nullptr, nullptr, S2);
    gemm_eval<1><<<gg, 256, 0, stream>>>(A, S2, S_h, nullptr, S3);
    gemm_eval<1><<<gg, 256, 0, stream>>>(A, S3, S2, nullptr, S4);
    gemm_eval<3><<<gg, 256, 0, stream>>>(A, S4, S3, S_h, S5);
    if (pass == 0)
      combine<0><<<dim3(58, 8, 2), 256, 0, stream>>>(S_h, S2, S3, S4, S5, Wt1, m1b, tmp);
    else
      combine<1><<<dim3(58, 8, 2), 256, 0, stream>>>(S_h, S2, S3, S4, S5, Wt2, m2b, tmp);
  }
  untranspose<<<dim3(64, 8, 8), 256, 0, stream>>>(tmp, out);
}

// Round 4
// 723.999 us; speedup vs baseline: 1.6063x; 1.2113x over previous
//
#include <hip/hip_runtime.h>
#include <math.h>

#define NN 512
#define BB 8
#define CC 64
#define TT 64
#define LL 58
#define CL (CC*LL)        // 3712
#define BCL (BB*CC*LL)    // 29696
#define SZ ((size_t)NN*BCL)   // 15,204,352 elements per state

typedef _Float16 half8 __attribute__((ext_vector_type(8)));
typedef _Float16 half4 __attribute__((ext_vector_type(4)));
typedef float f32x4 __attribute__((ext_vector_type(4)));

// ---------------- adjacency normalization ----------------
__global__ __launch_bounds__(64) void prep_adj(const float* __restrict__ adj,
                                               float* __restrict__ dinv1,
                                               float* __restrict__ dinv2){
  int v = blockIdx.x;
  int lane = threadIdx.x;
  float rs = 0.f, cs = 0.f;
  for (int w = lane; w < NN; w += 64){
    rs += adj[v*NN + w];
    cs += adj[w*NN + v];
  }
  for (int off = 32; off > 0; off >>= 1){
    rs += __shfl_down(rs, off);
    cs += __shfl_down(cs, off);
  }
  if (lane == 0){
    dinv1[v] = 1.f / sqrtf(rs + 1.f);
    dinv2[v] = 1.f / sqrtf(cs + 1.f);
  }
}

__global__ __launch_bounds__(256) void build_norm(const float* __restrict__ adj,
                                                  const float* __restrict__ dinv1,
                                                  const float* __restrict__ dinv2,
                                                  _Float16* __restrict__ An,
                                                  _Float16* __restrict__ AnT){
  int v = blockIdx.x;
  float d1v = dinv1[v], d2v = dinv2[v];
  for (int w = threadIdx.x; w < NN; w += 256){
    float diag = (v == w) ? 1.f : 0.f;
    An[v*NN + w]  = (_Float16)(d1v * (adj[v*NN + w] + diag) * dinv1[w]);
    AnT[v*NN + w] = (_Float16)(d2v * (adj[w*NN + v] + diag) * dinv2[w]);
  }
}

// ---------------- W cast: m1w/m2w fp32 [64][320] -> f16 same layout ----------------
__global__ __launch_bounds__(256) void wcat_prep(const float* __restrict__ W1,
                                                 const float* __restrict__ W2,
                                                 _Float16* __restrict__ Wc1,
                                                 _Float16* __restrict__ Wc2){
  int idx = blockIdx.x*256 + threadIdx.x;   // grid 80 -> 20480
  Wc1[idx] = (_Float16)W1[idx];
  Wc2[idx] = (_Float16)W2[idx];
}

// ---------------- inception weight prep ----------------
__global__ __launch_bounds__(448) void wfg_prep(
    const float* __restrict__ w10, const float* __restrict__ w11,
    const float* __restrict__ w12, const float* __restrict__ w13,
    const float* __restrict__ w20, const float* __restrict__ w21,
    const float* __restrict__ w22, const float* __restrict__ w23,
    const float* __restrict__ b10, const float* __restrict__ b11,
    const float* __restrict__ b12, const float* __restrict__ b13,
    const float* __restrict__ b20, const float* __restrict__ b21,
    const float* __restrict__ b22, const float* __restrict__ b23,
    _Float16* __restrict__ WfG, float* __restrict__ biasFG){
  int r = blockIdx.x;         // 0..127
  int t = threadIdx.x;        // 0..447
  int qp = t >> 6, ic = t & 63;
  int gate = r >> 6;
  int j = (r >> 4) & 3;
  int oc = r & 15;
  const int kjs[4] = {2, 3, 6, 7};
  int kj = kjs[j];
  const float* wsel = gate ? ((j==0)?w20:(j==1)?w21:(j==2)?w22:w23)
                           : ((j==0)?w10:(j==1)?w11:(j==2)?w12:w13);
  int off = 7 - kj;
  float val = (qp >= off) ? wsel[(oc*64 + ic)*kj + (qp - off)] : 0.f;
  WfG[(size_t)r*448 + t] = (_Float16)val;
  if (t == 0){
    const float* bsel = gate ? ((j==0)?b20:(j==1)?b21:(j==2)?b22:b23)
                             : ((j==0)?b10:(j==1)?b11:(j==2)?b12:b13);
    biasFG[r] = bsel[oc];
  }
}

// ---------------- x transpose: x[b][ic][n][t] f32 -> xTg[b][t][n][ic] f16 ----------------
__global__ __launch_bounds__(256) void xt_prep(const float* __restrict__ x,
                                               _Float16* __restrict__ xTg){
  __shared__ float T[64][65];
  int n = blockIdx.x;   // 512
  int b = blockIdx.y;   // 8
  int tid = threadIdx.x;
  #pragma unroll
  for (int r = 0; r < 4; ++r){
    int f = tid + r*256;       // 0..1023
    int ic = f >> 4, t4 = f & 15;
    float4 v = *(const float4*)&x[(((size_t)(b*64 + ic))*512 + n)*64 + t4*4];
    T[ic][t4*4+0] = v.x; T[ic][t4*4+1] = v.y;
    T[ic][t4*4+2] = v.z; T[ic][t4*4+3] = v.w;
  }
  __syncthreads();
  #pragma unroll
  for (int r = 0; r < 2; ++r){
    int f = tid + r*256;       // 0..511
    int t = f >> 3, ch = f & 7;
    half8 hv;
    #pragma unroll
    for (int q2 = 0; q2 < 8; ++q2) hv[q2] = (_Float16)T[ch*8 + q2][t];
    *(half8*)&xTg[(((size_t)(b*64 + t))*512 + n)*64 + ch*8] = hv;
  }
}

// ---------------- inception via MFMA ----------------
__global__ __launch_bounds__(256) void inception_mfma(
    const _Float16* __restrict__ xTg,   // [b][t][n][ic]
    const _Float16* __restrict__ WfG,   // [128][448]
    const float* __restrict__ biasFG,   // [128]
    _Float16* __restrict__ S_h){
  __shared__ _Float16 X[14*32*64];      // indexed in 8-half chunks
  int nt = blockIdx.x;   // 0..15
  int lt = blockIdx.y;   // 0..7
  int b  = blockIdx.z;   // 0..7
  int n0 = nt*32, l0 = lt*8;
  int tid = threadIdx.x;

  int sch = tid & 7, sn = (tid >> 3) & 31;
  #pragma unroll
  for (int r = 0; r < 14; ++r){
    int t = l0 + r;
    half8 v = {};
    if (t < 64)
      v = *(const half8*)&xTg[(((size_t)(b*64 + t))*512 + n0 + sn)*64 + sch*8];
    *(half8*)&X[(size_t)(r*256 + sn*8 + (sch ^ (sn & 7)))*8] = v;
  }

  int w = tid >> 6, lane = tid & 63;
  int m = lane & 15, kg = lane >> 4;

  half8 wF[14], wG[14];
  const _Float16* wb = WfG + (size_t)(w*16 + m)*448 + kg*8;
  #pragma unroll
  for (int s = 0; s < 14; ++s){
    wF[s] = *(const half8*)(wb + s*32);
    wG[s] = *(const half8*)(wb + (size_t)64*448 + s*32);
  }
  f32x4 bF = *(const f32x4*)&biasFG[w*16 + kg*4];
  f32x4 bG = *(const f32x4*)&biasFG[64 + w*16 + kg*4];

  __syncthreads();

  for (int ll = 0; ll < 8; ++ll){
    f32x4 aF0 = {}, aF1 = {}, aG0 = {}, aG1 = {};
    #pragma unroll
    for (int s = 0; s < 14; ++s){
      int t = ll + (s >> 1);
      int c0 = (s & 1)*4 + kg;
      half8 b0 = *(half8*)&X[(size_t)(t*256 + m*8        + (c0 ^ (m & 7)))*8];
      half8 b1 = *(half8*)&X[(size_t)(t*256 + (16+m)*8   + (c0 ^ (m & 7)))*8];
      aF0 = __builtin_amdgcn_mfma_f32_16x16x32_f16(wF[s], b0, aF0, 0, 0, 0);
      aG0 = __builtin_amdgcn_mfma_f32_16x16x32_f16(wG[s], b0, aG0, 0, 0, 0);
      aF1 = __builtin_amdgcn_mfma_f32_16x16x32_f16(wF[s], b1, aF1, 0, 0, 0);
      aG1 = __builtin_amdgcn_mfma_f32_16x16x32_f16(wG[s], b1, aG1, 0, 0, 0);
    }
    int l = l0 + ll;
    if (l < LL){
      #pragma unroll
      for (int rr = 0; rr < 4; ++rr){
        int c = w*16 + kg*4 + rr;
        float F0 = aF0[rr] + bF[rr];
        float G0 = aG0[rr] + bG[rr];
        float F1 = aF1[rr] + bF[rr];
        float G1 = aG1[rr] + bG[rr];
        float h0 = tanhf(F0) * (1.f / (1.f + expf(-G0)));
        float h1 = tanhf(F1) * (1.f / (1.f + expf(-G1)));
        size_t base = ((size_t)(b*64 + c)*LL + l)*NN + n0;
        S_h[base + m]      = (_Float16)h0;
        S_h[base + 16 + m] = (_Float16)h1;
      }
    }
  }
}

// ---------------- f-eval: O[m][v] = epi( G = An * S_in^T ) -------------
template<int MODE>
__global__ __launch_bounds__(256) void gemm_eval(
    const _Float16* __restrict__ A,    // [512][512] row v, col w
    const _Float16* __restrict__ Bst,  // state [m][w]
    const _Float16* __restrict__ P1,
    const _Float16* __restrict__ P2,
    _Float16* __restrict__ O){
  __shared__ _Float16 Ash[256][40];
  __shared__ _Float16 Bsh[64][40];
  int t = threadIdx.x;
  int m0 = blockIdx.x * 64;
  int v0 = blockIdx.y * 256;
  int w = t >> 6;
  int lane = t & 63;
  int lr = lane & 15;
  int koff = (lane >> 4) * 8;

  f32x4 acc[4][4] = {};

  for (int k0 = 0; k0 < NN; k0 += 32){
    half8 areg[4];
    #pragma unroll
    for (int i = 0; i < 4; ++i){
      int c = t + i*256;
      int r = c >> 2, sg = c & 3;
      areg[i] = *(const half8*)&A[(size_t)(v0 + r)*NN + k0 + sg*8];
    }
    int br = t >> 2, bsg = t & 3;
    half8 breg = *(const half8*)&Bst[(size_t)(m0 + br)*NN + k0 + bsg*8];

    __syncthreads();
    #pragma unroll
    for (int i = 0; i < 4; ++i){
      int c = t + i*256;
      int r = c >> 2, sg = c & 3;
      *(half8*)&Ash[r][sg*8] = areg[i];
    }
    *(half8*)&Bsh[br][bsg*8] = breg;
    __syncthreads();

    half8 af[4], bf[4];
    #pragma unroll
    for (int i = 0; i < 4; ++i) af[i] = *(half8*)&Ash[w*64 + i*16 + lr][koff];
    #pragma unroll
    for (int jj = 0; jj < 4; ++jj) bf[jj] = *(half8*)&Bsh[jj*16 + lr][koff];
    #pragma unroll
    for (int i = 0; i < 4; ++i)
      #pragma unroll
      for (int jj = 0; jj < 4; ++jj)
        acc[i][jj] = __builtin_amdgcn_mfma_f32_16x16x32_f16(af[i], bf[jj], acc[i][jj], 0, 0, 0);
  }

  int q = lane >> 4;
  #pragma unroll
  for (int i = 0; i < 4; ++i){
    #pragma unroll
    for (int jj = 0; jj < 4; ++jj){
      int vv = v0 + w*64 + i*16 + q*4;
      int mq = m0 + jj*16 + lr;
      size_t base = (size_t)mq*NN + vv;
      half4 bq = *(const half4*)(Bst + base);
      half4 p1q = {}, p2q = {};
      if (MODE >= 1) p1q = *(const half4*)(P1 + base);
      if (MODE == 3) p2q = *(const half4*)(P2 + base);
      half4 oq;
      #pragma unroll
      for (int rr = 0; rr < 4; ++rr){
        float G = acc[i][jj][rr];
        float bv = (float)bq[rr];
        float val;
        if (MODE == 0)      val = (1.f/3.f)*G + (2.f/3.f)*bv;
        else if (MODE == 1) val = G - 2.f*bv + 2.f*(float)p1q[rr];
        else                val = 0.125f*G + 0.25f*bv + 0.75f*(float)p1q[rr] - 0.125f*(float)p2q[rr];
        oq[rr] = (_Float16)val;
      }
      *(half4*)(O + base) = oq;
    }
  }
}

// ---------------- 1x1 mix via MFMA ----------------
// Per pass: tmp[((b*58+l)*64+o)*512+v] (+)= sum_{s,c} Wc[o][s*64+c]*S_s[(b,c,l)][v] + bias[o]
// Block: (v-half, l, b). A=W (o side), B=state tile via LDS (v side), K=320.
// Xsh row stride 258 halves: b-frag lanes (v,kg) land on all 32 banks 2-way (free).
template<int PASS>
__global__ __launch_bounds__(256) void combine_mfma(
    const _Float16* __restrict__ Sh, const _Float16* __restrict__ S2,
    const _Float16* __restrict__ S3, const _Float16* __restrict__ S4,
    const _Float16* __restrict__ Sf,
    const _Float16* __restrict__ Wc,   // [64][320] f16
    const float* __restrict__ bias,    // [64]
    _Float16* __restrict__ tmp){
  __shared__ _Float16 Xsh[64*258];
  __shared__ _Float16 Wsh[64*72];
  __shared__ float Bsh[64];
  int v0 = blockIdx.x * 256;
  int l  = blockIdx.y;
  int b  = blockIdx.z;
  int tid = threadIdx.x;
  int w = tid >> 6, lane = tid & 63;
  int lr = lane & 15, kg = lane >> 4;

  if (tid < 64) Bsh[tid] = bias[tid];

  const _Float16* Sarr[5] = {Sh, S2, S3, S4, Sf};
  f32x4 acc[4][4] = {};   // [vt][jj]

  for (int kt = 0; kt < 5; ++kt){
    const _Float16* S = Sarr[kt];
    __syncthreads();
    // stage X: 64 c-rows x 256 v
    #pragma unroll
    for (int r = 0; r < 8; ++r){
      int f = tid + r*256;        // 0..2047
      int c = f >> 5, ch = f & 31;
      half8 xv = *(const half8*)&S[((size_t)(b*64 + c)*58 + l)*512 + v0 + ch*8];
      *(half8*)&Xsh[c*258 + ch*8] = xv;
    }
    // stage W k-slice: 64 o-rows x 64 k
    #pragma unroll
    for (int r = 0; r < 2; ++r){
      int f = tid + r*256;        // 0..511
      int o = f >> 3, ch = f & 7;
      *(half8*)&Wsh[o*72 + ch*8] = *(const half8*)&Wc[(size_t)o*320 + kt*64 + ch*8];
    }
    __syncthreads();

    #pragma unroll
    for (int ks = 0; ks < 2; ++ks){
      int k0 = ks*32;
      half8 aW[4];
      #pragma unroll
      for (int jj = 0; jj < 4; ++jj)
        aW[jj] = *(half8*)&Wsh[(jj*16 + lr)*72 + k0 + kg*8];
      #pragma unroll
      for (int vt = 0; vt < 4; ++vt){
        half8 bX;
        #pragma unroll
        for (int j = 0; j < 8; ++j)
          bX[j] = Xsh[(k0 + kg*8 + j)*258 + w*64 + vt*16 + lr];
        #pragma unroll
        for (int jj = 0; jj < 4; ++jj)
          acc[vt][jj] = __builtin_amdgcn_mfma_f32_16x16x32_f16(aW[jj], bX, acc[vt][jj], 0, 0, 0);
      }
    }
  }

  // epilogue: D[o = jj*16 + kg*4 + rr][v = vt*16 + lr]
  size_t rowbase = ((size_t)b*58 + l)*64;
  #pragma unroll
  for (int jj = 0; jj < 4; ++jj){
    #pragma unroll
    for (int rr = 0; rr < 4; ++rr){
      int o = jj*16 + kg*4 + rr;
      float bv = Bsh[o];
      size_t obase = (rowbase + o)*512 + v0 + w*64 + lr;
      #pragma unroll
      for (int vt = 0; vt < 4; ++vt){
        float val = acc[vt][jj][rr] + bv;
        size_t addr = obase + vt*16;
        if (PASS == 0) tmp[addr] = (_Float16)val;
        else           tmp[addr] = (_Float16)((float)tmp[addr] + val);
      }
    }
  }
}

// ---------------- untranspose tmp[(b,l)][o][v] -> out[b][o][v][6+l], zero pad ----------------
__global__ __launch_bounds__(256) void untranspose(const _Float16* __restrict__ tmp,
                                                   float* __restrict__ out){
  __shared__ float T[58][65];
  int o = blockIdx.x;          // 64
  int b = blockIdx.y;          // 8
  int v0 = blockIdx.z * 64;    // 8
  int t = threadIdx.x;
  for (int idx = t; idx < 58*64; idx += 256){
    int lr = idx >> 6, vv = idx & 63;
    T[lr][vv] = (float)tmp[((size_t)(b*58 + lr)*64 + o)*NN + v0 + vv];
  }
  __syncthreads();
  #pragma unroll
  for (int i = 0; i < 16; ++i){
    int c = t + i*256;           // 0..4095
    int vv = c >> 6, tt = c & 63;
    float val = (tt < 6) ? 0.f : T[tt - 6][vv];
    out[((size_t)(b*64 + o)*NN + v0 + vv)*TT + tt] = val;
  }
}

// ---------------- launch ----------------
extern "C" void kernel_launch(void* const* d_in, const int* in_sizes, int n_in,
                              void* d_out, int out_size, void* d_ws, size_t ws_size,
                              hipStream_t stream){
  const float* x   = (const float*)d_in[0];
  const float* adj = (const float*)d_in[1];
  const float* w1[4] = {(const float*)d_in[2],  (const float*)d_in[4],
                        (const float*)d_in[6],  (const float*)d_in[8]};
  const float* b1[4] = {(const float*)d_in[3],  (const float*)d_in[5],
                        (const float*)d_in[7],  (const float*)d_in[9]};
  const float* w2[4] = {(const float*)d_in[10], (const float*)d_in[12],
                        (const float*)d_in[14], (const float*)d_in[16]};
  const float* b2[4] = {(const float*)d_in[11], (const float*)d_in[13],
                        (const float*)d_in[15], (const float*)d_in[17]};
  const float* m1w = (const float*)d_in[18];
  const float* m1b = (const float*)d_in[19];
  const float* m2w = (const float*)d_in[20];
  const float* m2b = (const float*)d_in[21];

  // workspace layout (bytes) — total ~184 MB (unchanged footprint)
  char* wsb = (char*)d_ws;
  float* dinv1 = (float*)(wsb);
  float* dinv2 = (float*)(wsb + 2048);
  _Float16* Wc1 = (_Float16*)(wsb + 4096);             // 40 KB
  _Float16* Wc2 = (_Float16*)(wsb + 4096 + 40960);     // 40 KB
  _Float16* An  = (_Float16*)(wsb + 167936);
  _Float16* AnT = (_Float16*)(wsb + 167936 + 524288);
  size_t sbytes = SZ * 2;
  char* sbase = wsb + 1216512;
  _Float16* S_h = (_Float16*)(sbase);
  _Float16* S2  = (_Float16*)(sbase + sbytes);
  _Float16* S3  = (_Float16*)(sbase + 2*sbytes);
  _Float16* S4  = (_Float16*)(sbase + 3*sbytes);
  _Float16* S5  = (_Float16*)(sbase + 4*sbytes);
  _Float16* tmp = (_Float16*)(sbase + 5*sbytes);
  _Float16* xTg = S2;   // dead before gemm_eval<0> writes S2
  _Float16* WfG = (_Float16*)(sbase + 6*sbytes);        // 114688 B
  float* biasFG = (float*)(sbase + 6*sbytes + 114688);  // 512 B
  float* out = (float*)d_out;

  prep_adj<<<NN, 64, 0, stream>>>(adj, dinv1, dinv2);
  build_norm<<<NN, 256, 0, stream>>>(adj, dinv1, dinv2, An, AnT);
  wcat_prep<<<80, 256, 0, stream>>>(m1w, m2w, Wc1, Wc2);
  wfg_prep<<<128, 448, 0, stream>>>(
      w1[0],w1[1],w1[2],w1[3], w2[0],w2[1],w2[2],w2[3],
      b1[0],b1[1],b1[2],b1[3], b2[0],b2[1],b2[2],b2[3], WfG, biasFG);
  xt_prep<<<dim3(NN, BB), 256, 0, stream>>>(x, xTg);
  inception_mfma<<<dim3(16, 8, 8), 256, 0, stream>>>(xTg, WfG, biasFG, S_h);

  dim3 gg(BCL/64, 2);
  dim3 gc(2, LL, BB);
  for (int pass = 0; pass < 2; ++pass){
    const _Float16* A = pass ? AnT : An;
    gemm_eval<0><<<gg, 256, 0, stream>>>(A, S_h, nullptr, nullptr, S2);
    gemm_eval<1><<<gg, 256, 0, stream>>>(A, S2, S_h, nullptr, S3);
    gemm_eval<1><<<gg, 256, 0, stream>>>(A, S3, S2, nullptr, S4);
    gemm_eval<3><<<gg, 256, 0, stream>>>(A, S4, S3, S_h, S5);
    if (pass == 0)
      combine_mfma<0><<<gc, 256, 0, stream>>>(S_h, S2, S3, S4, S5, Wc1, m1b, tmp);
    else
      combine_mfma<1><<<gc, 256, 0, stream>>>(S_h, S2, S3, S4, S5, Wc2, m2b, tmp);
  }
  untranspose<<<dim3(64, 8, 8), 256, 0, stream>>>(tmp, out);
}

// Round 5
// 621.594 us; speedup vs baseline: 1.8710x; 1.1647x over previous
//
#include <hip/hip_runtime.h>
#include <math.h>

#define NN 512
#define BB 8
#define CC 64
#define TT 64
#define LL 58
#define CL (CC*LL)        // 3712
#define BCL (BB*CC*LL)    // 29696
#define SZ ((size_t)NN*BCL)   // 15,204,352 elements per state

typedef _Float16 half8 __attribute__((ext_vector_type(8)));
typedef _Float16 half4 __attribute__((ext_vector_type(4)));
typedef float f32x4 __attribute__((ext_vector_type(4)));

// ---------------- adjacency normalization ----------------
__global__ __launch_bounds__(64) void prep_adj(const float* __restrict__ adj,
                                               float* __restrict__ dinv1,
                                               float* __restrict__ dinv2){
  int v = blockIdx.x;
  int lane = threadIdx.x;
  float rs = 0.f, cs = 0.f;
  for (int w = lane; w < NN; w += 64){
    rs += adj[v*NN + w];
    cs += adj[w*NN + v];
  }
  for (int off = 32; off > 0; off >>= 1){
    rs += __shfl_down(rs, off);
    cs += __shfl_down(cs, off);
  }
  if (lane == 0){
    dinv1[v] = 1.f / sqrtf(rs + 1.f);
    dinv2[v] = 1.f / sqrtf(cs + 1.f);
  }
}

// emits M = D^-1/2(A+I)D^-1/2 - I  (f(y) = M·y since 0.5*ALPHA = 1, DT=1)
__global__ __launch_bounds__(256) void build_norm(const float* __restrict__ adj,
                                                  const float* __restrict__ dinv1,
                                                  const float* __restrict__ dinv2,
                                                  _Float16* __restrict__ An,
                                                  _Float16* __restrict__ AnT){
  int v = blockIdx.x;
  float d1v = dinv1[v], d2v = dinv2[v];
  for (int w = threadIdx.x; w < NN; w += 256){
    float diag = (v == w) ? 1.f : 0.f;
    An[v*NN + w]  = (_Float16)(d1v * (adj[v*NN + w] + diag) * dinv1[w] - diag);
    AnT[v*NN + w] = (_Float16)(d2v * (adj[w*NN + v] + diag) * dinv2[w] - diag);
  }
}

// ---------------- U prep: fold RK/concat coefficients into combine weights ----
// U_p[o][d*64+c] = sum_s coef[d][s] * W_p[o][s*64+c]   (states s=[h,y2,y3,y4,yf])
__global__ __launch_bounds__(256) void u_prep(const float* __restrict__ W1,
                                              const float* __restrict__ W2,
                                              _Float16* __restrict__ U1,
                                              _Float16* __restrict__ U2){
  const float coef[5][5] = {
    {1.f, 1.f, 1.f, 1.f, 1.f},
    {0.f, 1.f/3.f, 2.f/3.f, 1.f, 1.f},
    {0.f, 0.f, 1.f/3.f, 1.f/3.f, 0.5f},
    {0.f, 0.f, 0.f, 1.f/3.f, 1.f/6.f},
    {0.f, 0.f, 0.f, 0.f, 1.f/24.f}};
  int idx = blockIdx.x*256 + threadIdx.x;   // grid 80 -> 20480
  int o = idx / 320, rem = idx - o*320;
  int d = rem >> 6, c = rem & 63;
  float a1 = 0.f, a2 = 0.f;
  #pragma unroll
  for (int s = 0; s < 5; ++s){
    float cf = coef[d][s];
    a1 += cf * W1[o*320 + s*64 + c];
    a2 += cf * W2[o*320 + s*64 + c];
  }
  U1[idx] = (_Float16)a1;
  U2[idx] = (_Float16)a2;
}

// ---------------- inception weight prep ----------------
__global__ __launch_bounds__(448) void wfg_prep(
    const float* __restrict__ w10, const float* __restrict__ w11,
    const float* __restrict__ w12, const float* __restrict__ w13,
    const float* __restrict__ w20, const float* __restrict__ w21,
    const float* __restrict__ w22, const float* __restrict__ w23,
    const float* __restrict__ b10, const float* __restrict__ b11,
    const float* __restrict__ b12, const float* __restrict__ b13,
    const float* __restrict__ b20, const float* __restrict__ b21,
    const float* __restrict__ b22, const float* __restrict__ b23,
    _Float16* __restrict__ WfG, float* __restrict__ biasFG){
  int r = blockIdx.x;         // 0..127
  int t = threadIdx.x;        // 0..447
  int qp = t >> 6, ic = t & 63;
  int gate = r >> 6;
  int j = (r >> 4) & 3;
  int oc = r & 15;
  const int kjs[4] = {2, 3, 6, 7};
  int kj = kjs[j];
  const float* wsel = gate ? ((j==0)?w20:(j==1)?w21:(j==2)?w22:w23)
                           : ((j==0)?w10:(j==1)?w11:(j==2)?w12:w13);
  int off = 7 - kj;
  float val = (qp >= off) ? wsel[(oc*64 + ic)*kj + (qp - off)] : 0.f;
  WfG[(size_t)r*448 + t] = (_Float16)val;
  if (t == 0){
    const float* bsel = gate ? ((j==0)?b20:(j==1)?b21:(j==2)?b22:b23)
                             : ((j==0)?b10:(j==1)?b11:(j==2)?b12:b13);
    biasFG[r] = bsel[oc];
  }
}

// ---------------- x transpose: x[b][ic][n][t] f32 -> xTg[b][t][n][ic] f16 ----------------
__global__ __launch_bounds__(256) void xt_prep(const float* __restrict__ x,
                                               _Float16* __restrict__ xTg){
  __shared__ float T[64][65];
  int n = blockIdx.x;   // 512
  int b = blockIdx.y;   // 8
  int tid = threadIdx.x;
  #pragma unroll
  for (int r = 0; r < 4; ++r){
    int f = tid + r*256;       // 0..1023
    int ic = f >> 4, t4 = f & 15;
    float4 v = *(const float4*)&x[(((size_t)(b*64 + ic))*512 + n)*64 + t4*4];
    T[ic][t4*4+0] = v.x; T[ic][t4*4+1] = v.y;
    T[ic][t4*4+2] = v.z; T[ic][t4*4+3] = v.w;
  }
  __syncthreads();
  #pragma unroll
  for (int r = 0; r < 2; ++r){
    int f = tid + r*256;       // 0..511
    int t = f >> 3, ch = f & 7;
    half8 hv;
    #pragma unroll
    for (int q2 = 0; q2 < 8; ++q2) hv[q2] = (_Float16)T[ch*8 + q2][t];
    *(half8*)&xTg[(((size_t)(b*64 + t))*512 + n)*64 + ch*8] = hv;
  }
}

// ---------------- inception via MFMA ----------------
__global__ __launch_bounds__(256) void inception_mfma(
    const _Float16* __restrict__ xTg,   // [b][t][n][ic]
    const _Float16* __restrict__ WfG,   // [128][448]
    const float* __restrict__ biasFG,   // [128]
    _Float16* __restrict__ S_h){
  __shared__ _Float16 X[14*32*64];      // indexed in 8-half chunks
  int nt = blockIdx.x;   // 0..15
  int lt = blockIdx.y;   // 0..7
  int b  = blockIdx.z;   // 0..7
  int n0 = nt*32, l0 = lt*8;
  int tid = threadIdx.x;

  int sch = tid & 7, sn = (tid >> 3) & 31;
  #pragma unroll
  for (int r = 0; r < 14; ++r){
    int t = l0 + r;
    half8 v = {};
    if (t < 64)
      v = *(const half8*)&xTg[(((size_t)(b*64 + t))*512 + n0 + sn)*64 + sch*8];
    *(half8*)&X[(size_t)(r*256 + sn*8 + (sch ^ (sn & 7)))*8] = v;
  }

  int w = tid >> 6, lane = tid & 63;
  int m = lane & 15, kg = lane >> 4;

  half8 wF[14], wG[14];
  const _Float16* wb = WfG + (size_t)(w*16 + m)*448 + kg*8;
  #pragma unroll
  for (int s = 0; s < 14; ++s){
    wF[s] = *(const half8*)(wb + s*32);
    wG[s] = *(const half8*)(wb + (size_t)64*448 + s*32);
  }
  f32x4 bF = *(const f32x4*)&biasFG[w*16 + kg*4];
  f32x4 bG = *(const f32x4*)&biasFG[64 + w*16 + kg*4];

  __syncthreads();

  for (int ll = 0; ll < 8; ++ll){
    f32x4 aF0 = {}, aF1 = {}, aG0 = {}, aG1 = {};
    #pragma unroll
    for (int s = 0; s < 14; ++s){
      int t = ll + (s >> 1);
      int c0 = (s & 1)*4 + kg;
      half8 b0 = *(half8*)&X[(size_t)(t*256 + m*8        + (c0 ^ (m & 7)))*8];
      half8 b1 = *(half8*)&X[(size_t)(t*256 + (16+m)*8   + (c0 ^ (m & 7)))*8];
      aF0 = __builtin_amdgcn_mfma_f32_16x16x32_f16(wF[s], b0, aF0, 0, 0, 0);
      aG0 = __builtin_amdgcn_mfma_f32_16x16x32_f16(wG[s], b0, aG0, 0, 0, 0);
      aF1 = __builtin_amdgcn_mfma_f32_16x16x32_f16(wF[s], b1, aF1, 0, 0, 0);
      aG1 = __builtin_amdgcn_mfma_f32_16x16x32_f16(wG[s], b1, aG1, 0, 0, 0);
    }
    int l = l0 + ll;
    if (l < LL){
      #pragma unroll
      for (int rr = 0; rr < 4; ++rr){
        int c = w*16 + kg*4 + rr;
        float F0 = aF0[rr] + bF[rr];
        float G0 = aG0[rr] + bG[rr];
        float F1 = aF1[rr] + bF[rr];
        float G1 = aG1[rr] + bG[rr];
        float h0 = tanhf(F0) * (1.f / (1.f + expf(-G0)));
        float h1 = tanhf(F1) * (1.f / (1.f + expf(-G1)));
        size_t base = ((size_t)(b*64 + c)*LL + l)*NN + n0;
        S_h[base + m]      = (_Float16)h0;
        S_h[base + 16 + m] = (_Float16)h1;
      }
    }
  }
}

// ---------------- Krylov step: O[m][v] = sum_w A[v][w] * Bst[m][w]  (pure GEMM)
__global__ __launch_bounds__(256) void gemm_z(
    const _Float16* __restrict__ A,    // [512][512] row v, col w  (M or M^T)
    const _Float16* __restrict__ Bst,  // z_{d-1}: [m][w]
    _Float16* __restrict__ O){         // z_d: [m][v]
  __shared__ _Float16 Ash[256][40];
  __shared__ _Float16 Bsh[64][40];
  int t = threadIdx.x;
  int m0 = blockIdx.x * 64;
  int v0 = blockIdx.y * 256;
  int w = t >> 6;
  int lane = t & 63;
  int lr = lane & 15;
  int koff = (lane >> 4) * 8;

  f32x4 acc[4][4] = {};

  for (int k0 = 0; k0 < NN; k0 += 32){
    half8 areg[4];
    #pragma unroll
    for (int i = 0; i < 4; ++i){
      int c = t + i*256;
      int r = c >> 2, sg = c & 3;
      areg[i] = *(const half8*)&A[(size_t)(v0 + r)*NN + k0 + sg*8];
    }
    int br = t >> 2, bsg = t & 3;
    half8 breg = *(const half8*)&Bst[(size_t)(m0 + br)*NN + k0 + bsg*8];

    __syncthreads();
    #pragma unroll
    for (int i = 0; i < 4; ++i){
      int c = t + i*256;
      int r = c >> 2, sg = c & 3;
      *(half8*)&Ash[r][sg*8] = areg[i];
    }
    *(half8*)&Bsh[br][bsg*8] = breg;
    __syncthreads();

    half8 af[4], bf[4];
    #pragma unroll
    for (int i = 0; i < 4; ++i) af[i] = *(half8*)&Ash[w*64 + i*16 + lr][koff];
    #pragma unroll
    for (int jj = 0; jj < 4; ++jj) bf[jj] = *(half8*)&Bsh[jj*16 + lr][koff];
    #pragma unroll
    for (int i = 0; i < 4; ++i)
      #pragma unroll
      for (int jj = 0; jj < 4; ++jj)
        acc[i][jj] = __builtin_amdgcn_mfma_f32_16x16x32_f16(af[i], bf[jj], acc[i][jj], 0, 0, 0);
  }

  int q = lane >> 4;
  #pragma unroll
  for (int i = 0; i < 4; ++i){
    #pragma unroll
    for (int jj = 0; jj < 4; ++jj){
      int vv = v0 + w*64 + i*16 + q*4;
      int mq = m0 + jj*16 + lr;
      size_t base = (size_t)mq*NN + vv;
      half4 oq;
      #pragma unroll
      for (int rr = 0; rr < 4; ++rr)
        oq[rr] = (_Float16)acc[i][jj][rr];
      *(half4*)(O + base) = oq;
    }
  }
}

// ---------------- 1x1 mix via MFMA over Krylov basis ----------------
// tmp[((b*58+l)*64+o)*512+v] (+)= sum_{d,c} U[o][d*64+c]*z_d[(b,c,l)][v] + bias[o]
template<int PASS>
__global__ __launch_bounds__(256) void combine_mfma(
    const _Float16* __restrict__ Sh, const _Float16* __restrict__ S2,
    const _Float16* __restrict__ S3, const _Float16* __restrict__ S4,
    const _Float16* __restrict__ Sf,
    const _Float16* __restrict__ Wc,   // U_p [64][320] f16
    const float* __restrict__ bias,    // [64]
    _Float16* __restrict__ tmp){
  __shared__ _Float16 Xsh[64*258];
  __shared__ _Float16 Wsh[64*72];
  __shared__ float Bsh[64];
  int v0 = blockIdx.x * 256;
  int l  = blockIdx.y;
  int b  = blockIdx.z;
  int tid = threadIdx.x;
  int w = tid >> 6, lane = tid & 63;
  int lr = lane & 15, kg = lane >> 4;

  if (tid < 64) Bsh[tid] = bias[tid];

  const _Float16* Sarr[5] = {Sh, S2, S3, S4, Sf};
  f32x4 acc[4][4] = {};   // [vt][jj]

  for (int kt = 0; kt < 5; ++kt){
    const _Float16* S = Sarr[kt];
    __syncthreads();
    #pragma unroll
    for (int r = 0; r < 8; ++r){
      int f = tid + r*256;        // 0..2047
      int c = f >> 5, ch = f & 31;
      half8 xv = *(const half8*)&S[((size_t)(b*64 + c)*58 + l)*512 + v0 + ch*8];
      *(half8*)&Xsh[c*258 + ch*8] = xv;
    }
    #pragma unroll
    for (int r = 0; r < 2; ++r){
      int f = tid + r*256;        // 0..511
      int o = f >> 3, ch = f & 7;
      *(half8*)&Wsh[o*72 + ch*8] = *(const half8*)&Wc[(size_t)o*320 + kt*64 + ch*8];
    }
    __syncthreads();

    #pragma unroll
    for (int ks = 0; ks < 2; ++ks){
      int k0 = ks*32;
      half8 aW[4];
      #pragma unroll
      for (int jj = 0; jj < 4; ++jj)
        aW[jj] = *(half8*)&Wsh[(jj*16 + lr)*72 + k0 + kg*8];
      #pragma unroll
      for (int vt = 0; vt < 4; ++vt){
        half8 bX;
        #pragma unroll
        for (int j = 0; j < 8; ++j)
          bX[j] = Xsh[(k0 + kg*8 + j)*258 + w*64 + vt*16 + lr];
        #pragma unroll
        for (int jj = 0; jj < 4; ++jj)
          acc[vt][jj] = __builtin_amdgcn_mfma_f32_16x16x32_f16(aW[jj], bX, acc[vt][jj], 0, 0, 0);
      }
    }
  }

  size_t rowbase = ((size_t)b*58 + l)*64;
  #pragma unroll
  for (int jj = 0; jj < 4; ++jj){
    #pragma unroll
    for (int rr = 0; rr < 4; ++rr){
      int o = jj*16 + kg*4 + rr;
      float bv = Bsh[o];
      size_t obase = (rowbase + o)*512 + v0 + w*64 + lr;
      #pragma unroll
      for (int vt = 0; vt < 4; ++vt){
        float val = acc[vt][jj][rr] + bv;
        size_t addr = obase + vt*16;
        if (PASS == 0) tmp[addr] = (_Float16)val;
        else           tmp[addr] = (_Float16)((float)tmp[addr] + val);
      }
    }
  }
}

// ---------------- untranspose tmp[(b,l)][o][v] -> out[b][o][v][6+l], zero pad ----------------
__global__ __launch_bounds__(256) void untranspose(const _Float16* __restrict__ tmp,
                                                   float* __restrict__ out){
  __shared__ float T[58][65];
  int o = blockIdx.x;          // 64
  int b = blockIdx.y;          // 8
  int v0 = blockIdx.z * 64;    // 8
  int t = threadIdx.x;
  for (int idx = t; idx < 58*64; idx += 256){
    int lr = idx >> 6, vv = idx & 63;
    T[lr][vv] = (float)tmp[((size_t)(b*58 + lr)*64 + o)*NN + v0 + vv];
  }
  __syncthreads();
  #pragma unroll
  for (int i = 0; i < 16; ++i){
    int c = t + i*256;           // 0..4095
    int vv = c >> 6, tt = c & 63;
    float val = (tt < 6) ? 0.f : T[tt - 6][vv];
    out[((size_t)(b*64 + o)*NN + v0 + vv)*TT + tt] = val;
  }
}

// ---------------- launch ----------------
extern "C" void kernel_launch(void* const* d_in, const int* in_sizes, int n_in,
                              void* d_out, int out_size, void* d_ws, size_t ws_size,
                              hipStream_t stream){
  const float* x   = (const float*)d_in[0];
  const float* adj = (const float*)d_in[1];
  const float* w1[4] = {(const float*)d_in[2],  (const float*)d_in[4],
                        (const float*)d_in[6],  (const float*)d_in[8]};
  const float* b1[4] = {(const float*)d_in[3],  (const float*)d_in[5],
                        (const float*)d_in[7],  (const float*)d_in[9]};
  const float* w2[4] = {(const float*)d_in[10], (const float*)d_in[12],
                        (const float*)d_in[14], (const float*)d_in[16]};
  const float* b2[4] = {(const float*)d_in[11], (const float*)d_in[13],
                        (const float*)d_in[15], (const float*)d_in[17]};
  const float* m1w = (const float*)d_in[18];
  const float* m1b = (const float*)d_in[19];
  const float* m2w = (const float*)d_in[20];
  const float* m2b = (const float*)d_in[21];

  // workspace layout (bytes) — total ~184 MB (unchanged footprint)
  char* wsb = (char*)d_ws;
  float* dinv1 = (float*)(wsb);
  float* dinv2 = (float*)(wsb + 2048);
  _Float16* U1  = (_Float16*)(wsb + 4096);             // 40 KB
  _Float16* U2  = (_Float16*)(wsb + 4096 + 40960);     // 40 KB
  _Float16* Mn  = (_Float16*)(wsb + 167936);           // M = An - I
  _Float16* MnT = (_Float16*)(wsb + 167936 + 524288);
  size_t sbytes = SZ * 2;
  char* sbase = wsb + 1216512;
  _Float16* S_h = (_Float16*)(sbase);                  // z0 = h
  _Float16* S2  = (_Float16*)(sbase + sbytes);         // z1
  _Float16* S3  = (_Float16*)(sbase + 2*sbytes);       // z2
  _Float16* S4  = (_Float16*)(sbase + 3*sbytes);       // z3
  _Float16* S5  = (_Float16*)(sbase + 4*sbytes);       // z4
  _Float16* tmp = (_Float16*)(sbase + 5*sbytes);
  _Float16* xTg = S2;   // dead before first gemm_z writes S2
  _Float16* WfG = (_Float16*)(sbase + 6*sbytes);        // 114688 B
  float* biasFG = (float*)(sbase + 6*sbytes + 114688);  // 512 B
  float* out = (float*)d_out;

  prep_adj<<<NN, 64, 0, stream>>>(adj, dinv1, dinv2);
  build_norm<<<NN, 256, 0, stream>>>(adj, dinv1, dinv2, Mn, MnT);
  u_prep<<<80, 256, 0, stream>>>(m1w, m2w, U1, U2);
  wfg_prep<<<128, 448, 0, stream>>>(
      w1[0],w1[1],w1[2],w1[3], w2[0],w2[1],w2[2],w2[3],
      b1[0],b1[1],b1[2],b1[3], b2[0],b2[1],b2[2],b2[3], WfG, biasFG);
  xt_prep<<<dim3(NN, BB), 256, 0, stream>>>(x, xTg);
  inception_mfma<<<dim3(16, 8, 8), 256, 0, stream>>>(xTg, WfG, biasFG, S_h);

  dim3 gg(BCL/64, 2);
  dim3 gc(2, LL, BB);
  for (int pass = 0; pass < 2; ++pass){
    const _Float16* A = pass ? MnT : Mn;
    gemm_z<<<gg, 256, 0, stream>>>(A, S_h, S2);
    gemm_z<<<gg, 256, 0, stream>>>(A, S2,  S3);
    gemm_z<<<gg, 256, 0, stream>>>(A, S3,  S4);
    gemm_z<<<gg, 256, 0, stream>>>(A, S4,  S5);
    if (pass == 0)
      combine_mfma<0><<<gc, 256, 0, stream>>>(S_h, S2, S3, S4, S5, U1, m1b, tmp);
    else
      combine_mfma<1><<<gc, 256, 0, stream>>>(S_h, S2, S3, S4, S5, U2, m2b, tmp);
  }
  untranspose<<<dim3(64, 8, 8), 256, 0, stream>>>(tmp, out);
}

// Round 6
// 583.393 us; speedup vs baseline: 1.9935x; 1.0655x over previous
//
#include <hip/hip_runtime.h>
#include <math.h>

#define NN 512
#define BB 8
#define CC 64
#define TT 64
#define LL 58
#define CL (CC*LL)        // 3712
#define BCL (BB*CC*LL)    // 29696
#define SZ ((size_t)NN*BCL)   // 15,204,352 elements per state

typedef _Float16 half8 __attribute__((ext_vector_type(8)));
typedef _Float16 half4 __attribute__((ext_vector_type(4)));
typedef float f32x4 __attribute__((ext_vector_type(4)));

// ---------------- adjacency normalization ----------------
__global__ __launch_bounds__(64) void prep_adj(const float* __restrict__ adj,
                                               float* __restrict__ dinv1,
                                               float* __restrict__ dinv2){
  int v = blockIdx.x;
  int lane = threadIdx.x;
  float rs = 0.f, cs = 0.f;
  for (int w = lane; w < NN; w += 64){
    rs += adj[v*NN + w];
    cs += adj[w*NN + v];
  }
  for (int off = 32; off > 0; off >>= 1){
    rs += __shfl_down(rs, off);
    cs += __shfl_down(cs, off);
  }
  if (lane == 0){
    dinv1[v] = 1.f / sqrtf(rs + 1.f);
    dinv2[v] = 1.f / sqrtf(cs + 1.f);
  }
}

// emits M = D^-1/2(A+I)D^-1/2 - I  (f(y) = M·y since 0.5*ALPHA = 1, DT=1)
__global__ __launch_bounds__(256) void build_norm(const float* __restrict__ adj,
                                                  const float* __restrict__ dinv1,
                                                  const float* __restrict__ dinv2,
                                                  _Float16* __restrict__ An,
                                                  _Float16* __restrict__ AnT){
  int v = blockIdx.x;
  float d1v = dinv1[v], d2v = dinv2[v];
  for (int w = threadIdx.x; w < NN; w += 256){
    float diag = (v == w) ? 1.f : 0.f;
    An[v*NN + w]  = (_Float16)(d1v * (adj[v*NN + w] + diag) * dinv1[w] - diag);
    AnT[v*NN + w] = (_Float16)(d2v * (adj[w*NN + v] + diag) * dinv2[w] - diag);
  }
}

// ---------------- U prep: fold RK/concat coefficients into combine weights ----
__global__ __launch_bounds__(256) void u_prep(const float* __restrict__ W1,
                                              const float* __restrict__ W2,
                                              _Float16* __restrict__ U1,
                                              _Float16* __restrict__ U2){
  const float coef[5][5] = {
    {1.f, 1.f, 1.f, 1.f, 1.f},
    {0.f, 1.f/3.f, 2.f/3.f, 1.f, 1.f},
    {0.f, 0.f, 1.f/3.f, 1.f/3.f, 0.5f},
    {0.f, 0.f, 0.f, 1.f/3.f, 1.f/6.f},
    {0.f, 0.f, 0.f, 0.f, 1.f/24.f}};
  int idx = blockIdx.x*256 + threadIdx.x;   // grid 80 -> 20480
  int o = idx / 320, rem = idx - o*320;
  int d = rem >> 6, c = rem & 63;
  float a1 = 0.f, a2 = 0.f;
  #pragma unroll
  for (int s = 0; s < 5; ++s){
    float cf = coef[d][s];
    a1 += cf * W1[o*320 + s*64 + c];
    a2 += cf * W2[o*320 + s*64 + c];
  }
  U1[idx] = (_Float16)a1;
  U2[idx] = (_Float16)a2;
}

// ---------------- inception weight prep ----------------
__global__ __launch_bounds__(448) void wfg_prep(
    const float* __restrict__ w10, const float* __restrict__ w11,
    const float* __restrict__ w12, const float* __restrict__ w13,
    const float* __restrict__ w20, const float* __restrict__ w21,
    const float* __restrict__ w22, const float* __restrict__ w23,
    const float* __restrict__ b10, const float* __restrict__ b11,
    const float* __restrict__ b12, const float* __restrict__ b13,
    const float* __restrict__ b20, const float* __restrict__ b21,
    const float* __restrict__ b22, const float* __restrict__ b23,
    _Float16* __restrict__ WfG, float* __restrict__ biasFG){
  int r = blockIdx.x;         // 0..127
  int t = threadIdx.x;        // 0..447
  int qp = t >> 6, ic = t & 63;
  int gate = r >> 6;
  int j = (r >> 4) & 3;
  int oc = r & 15;
  const int kjs[4] = {2, 3, 6, 7};
  int kj = kjs[j];
  const float* wsel = gate ? ((j==0)?w20:(j==1)?w21:(j==2)?w22:w23)
                           : ((j==0)?w10:(j==1)?w11:(j==2)?w12:w13);
  int off = 7 - kj;
  float val = (qp >= off) ? wsel[(oc*64 + ic)*kj + (qp - off)] : 0.f;
  WfG[(size_t)r*448 + t] = (_Float16)val;
  if (t == 0){
    const float* bsel = gate ? ((j==0)?b20:(j==1)?b21:(j==2)?b22:b23)
                             : ((j==0)?b10:(j==1)?b11:(j==2)?b12:b13);
    biasFG[r] = bsel[oc];
  }
}

// ---------------- x transpose: x[b][ic][n][t] f32 -> xTg[b][t][n][ic] f16 ----------------
__global__ __launch_bounds__(256) void xt_prep(const float* __restrict__ x,
                                               _Float16* __restrict__ xTg){
  __shared__ float T[64][65];
  int n = blockIdx.x;   // 512
  int b = blockIdx.y;   // 8
  int tid = threadIdx.x;
  #pragma unroll
  for (int r = 0; r < 4; ++r){
    int f = tid + r*256;       // 0..1023
    int ic = f >> 4, t4 = f & 15;
    float4 v = *(const float4*)&x[(((size_t)(b*64 + ic))*512 + n)*64 + t4*4];
    T[ic][t4*4+0] = v.x; T[ic][t4*4+1] = v.y;
    T[ic][t4*4+2] = v.z; T[ic][t4*4+3] = v.w;
  }
  __syncthreads();
  #pragma unroll
  for (int r = 0; r < 2; ++r){
    int f = tid + r*256;       // 0..511
    int t = f >> 3, ch = f & 7;
    half8 hv;
    #pragma unroll
    for (int q2 = 0; q2 < 8; ++q2) hv[q2] = (_Float16)T[ch*8 + q2][t];
    *(half8*)&xTg[(((size_t)(b*64 + t))*512 + n)*64 + ch*8] = hv;
  }
}

// ---------------- inception via MFMA ----------------
// Block: (n-tile 32, l-tile 7, b). GEMM M=128 (64F+64G), K=448, cols = 7l x 32n.
// LDS X[t=13][n=32][ic=64] f16, 16B-chunk xor-swizzled. 53248 B -> 3 blocks/CU.
// __launch_bounds__(256,3): VGPR cap 168 so the 112-VGPR weight set stays resident.
__global__ __launch_bounds__(256, 3) void inception_mfma(
    const _Float16* __restrict__ xTg,   // [b][t][n][ic]
    const _Float16* __restrict__ WfG,   // [128][448]
    const float* __restrict__ biasFG,   // [128]
    _Float16* __restrict__ S_h){
  __shared__ _Float16 X[13*32*64];      // indexed in 8-half chunks
  int nt = blockIdx.x;   // 0..15
  int lt = blockIdx.y;   // 0..8
  int b  = blockIdx.z;   // 0..7
  int n0 = nt*32, l0 = lt*7;
  int tid = threadIdx.x;

  int sch = tid & 7, sn = (tid >> 3) & 31;
  #pragma unroll
  for (int r = 0; r < 13; ++r){
    int t = l0 + r;
    half8 v = {};
    if (t < 64)
      v = *(const half8*)&xTg[(((size_t)(b*64 + t))*512 + n0 + sn)*64 + sch*8];
    *(half8*)&X[(size_t)(r*256 + sn*8 + (sch ^ (sn & 7)))*8] = v;
  }

  int w = tid >> 6, lane = tid & 63;
  int m = lane & 15, kg = lane >> 4;

  half8 wF[14], wG[14];
  const _Float16* wb = WfG + (size_t)(w*16 + m)*448 + kg*8;
  #pragma unroll
  for (int s = 0; s < 14; ++s){
    wF[s] = *(const half8*)(wb + s*32);
    wG[s] = *(const half8*)(wb + (size_t)64*448 + s*32);
  }
  f32x4 bF = *(const f32x4*)&biasFG[w*16 + kg*4];
  f32x4 bG = *(const f32x4*)&biasFG[64 + w*16 + kg*4];

  __syncthreads();

  for (int ll = 0; ll < 7; ++ll){
    f32x4 aF0 = {}, aF1 = {}, aG0 = {}, aG1 = {};
    #pragma unroll
    for (int s = 0; s < 14; ++s){
      int t = ll + (s >> 1);
      int c0 = (s & 1)*4 + kg;
      half8 b0 = *(half8*)&X[(size_t)(t*256 + m*8        + (c0 ^ (m & 7)))*8];
      half8 b1 = *(half8*)&X[(size_t)(t*256 + (16+m)*8   + (c0 ^ (m & 7)))*8];
      aF0 = __builtin_amdgcn_mfma_f32_16x16x32_f16(wF[s], b0, aF0, 0, 0, 0);
      aG0 = __builtin_amdgcn_mfma_f32_16x16x32_f16(wG[s], b0, aG0, 0, 0, 0);
      aF1 = __builtin_amdgcn_mfma_f32_16x16x32_f16(wF[s], b1, aF1, 0, 0, 0);
      aG1 = __builtin_amdgcn_mfma_f32_16x16x32_f16(wG[s], b1, aG1, 0, 0, 0);
    }
    int l = l0 + ll;
    if (l < LL){
      #pragma unroll
      for (int rr = 0; rr < 4; ++rr){
        int c = w*16 + kg*4 + rr;
        float F0 = aF0[rr] + bF[rr];
        float G0 = aG0[rr] + bG[rr];
        float F1 = aF1[rr] + bF[rr];
        float G1 = aG1[rr] + bG[rr];
        // fast tanh/sigmoid: v_exp + v_rcp
        float h0 = (2.f*__builtin_amdgcn_rcpf(1.f + __expf(-2.f*F0)) - 1.f)
                 * __builtin_amdgcn_rcpf(1.f + __expf(-G0));
        float h1 = (2.f*__builtin_amdgcn_rcpf(1.f + __expf(-2.f*F1)) - 1.f)
                 * __builtin_amdgcn_rcpf(1.f + __expf(-G1));
        size_t base = ((size_t)(b*64 + c)*LL + l)*NN + n0;
        S_h[base + m]      = (_Float16)h0;
        S_h[base + 16 + m] = (_Float16)h1;
      }
    }
  }
}

// ---------------- dual Krylov GEMM: two independent O=epi-free GEMMs per launch
// z-slot selects (A,B,O). O[m][v] = sum_w A[v][w] * B[m][w].
__global__ __launch_bounds__(256) void gemm_z2(
    const _Float16* __restrict__ A0, const _Float16* __restrict__ B0,
    _Float16* __restrict__ O0,
    const _Float16* __restrict__ A1, const _Float16* __restrict__ B1,
    _Float16* __restrict__ O1){
  const _Float16* A  = blockIdx.z ? A1 : A0;
  const _Float16* Bst = blockIdx.z ? B1 : B0;
  _Float16* O = blockIdx.z ? O1 : O0;

  __shared__ _Float16 Ash[256][40];
  __shared__ _Float16 Bsh[64][40];
  int t = threadIdx.x;
  int m0 = blockIdx.x * 64;
  int v0 = blockIdx.y * 256;
  int w = t >> 6;
  int lane = t & 63;
  int lr = lane & 15;
  int koff = (lane >> 4) * 8;

  f32x4 acc[4][4] = {};

  for (int k0 = 0; k0 < NN; k0 += 32){
    half8 areg[4];
    #pragma unroll
    for (int i = 0; i < 4; ++i){
      int c = t + i*256;
      int r = c >> 2, sg = c & 3;
      areg[i] = *(const half8*)&A[(size_t)(v0 + r)*NN + k0 + sg*8];
    }
    int br = t >> 2, bsg = t & 3;
    half8 breg = *(const half8*)&Bst[(size_t)(m0 + br)*NN + k0 + bsg*8];

    __syncthreads();
    #pragma unroll
    for (int i = 0; i < 4; ++i){
      int c = t + i*256;
      int r = c >> 2, sg = c & 3;
      *(half8*)&Ash[r][sg*8] = areg[i];
    }
    *(half8*)&Bsh[br][bsg*8] = breg;
    __syncthreads();

    half8 af[4], bf[4];
    #pragma unroll
    for (int i = 0; i < 4; ++i) af[i] = *(half8*)&Ash[w*64 + i*16 + lr][koff];
    #pragma unroll
    for (int jj = 0; jj < 4; ++jj) bf[jj] = *(half8*)&Bsh[jj*16 + lr][koff];
    #pragma unroll
    for (int i = 0; i < 4; ++i)
      #pragma unroll
      for (int jj = 0; jj < 4; ++jj)
        acc[i][jj] = __builtin_amdgcn_mfma_f32_16x16x32_f16(af[i], bf[jj], acc[i][jj], 0, 0, 0);
  }

  int q = lane >> 4;
  #pragma unroll
  for (int i = 0; i < 4; ++i){
    #pragma unroll
    for (int jj = 0; jj < 4; ++jj){
      int vv = v0 + w*64 + i*16 + q*4;
      int mq = m0 + jj*16 + lr;
      size_t base = (size_t)mq*NN + vv;
      half4 oq;
      #pragma unroll
      for (int rr = 0; rr < 4; ++rr)
        oq[rr] = (_Float16)acc[i][jj][rr];
      *(half4*)(O + base) = oq;
    }
  }
}

// ---------------- 1x1 mix via MFMA over Krylov basis ----------------
template<int PASS>
__global__ __launch_bounds__(256) void combine_mfma(
    const _Float16* __restrict__ Sh, const _Float16* __restrict__ S2,
    const _Float16* __restrict__ S3, const _Float16* __restrict__ S4,
    const _Float16* __restrict__ Sf,
    const _Float16* __restrict__ Wc,   // U_p [64][320] f16
    const float* __restrict__ bias,    // [64]
    _Float16* __restrict__ tmp){
  __shared__ _Float16 Xsh[64*258];
  __shared__ _Float16 Wsh[64*72];
  __shared__ float Bsh[64];
  int v0 = blockIdx.x * 256;
  int l  = blockIdx.y;
  int b  = blockIdx.z;
  int tid = threadIdx.x;
  int w = tid >> 6, lane = tid & 63;
  int lr = lane & 15, kg = lane >> 4;

  if (tid < 64) Bsh[tid] = bias[tid];

  const _Float16* Sarr[5] = {Sh, S2, S3, S4, Sf};
  f32x4 acc[4][4] = {};   // [vt][jj]

  for (int kt = 0; kt < 5; ++kt){
    const _Float16* S = Sarr[kt];
    __syncthreads();
    #pragma unroll
    for (int r = 0; r < 8; ++r){
      int f = tid + r*256;        // 0..2047
      int c = f >> 5, ch = f & 31;
      half8 xv = *(const half8*)&S[((size_t)(b*64 + c)*58 + l)*512 + v0 + ch*8];
      *(half8*)&Xsh[c*258 + ch*8] = xv;
    }
    #pragma unroll
    for (int r = 0; r < 2; ++r){
      int f = tid + r*256;        // 0..511
      int o = f >> 3, ch = f & 7;
      *(half8*)&Wsh[o*72 + ch*8] = *(const half8*)&Wc[(size_t)o*320 + kt*64 + ch*8];
    }
    __syncthreads();

    #pragma unroll
    for (int ks = 0; ks < 2; ++ks){
      int k0 = ks*32;
      half8 aW[4];
      #pragma unroll
      for (int jj = 0; jj < 4; ++jj)
        aW[jj] = *(half8*)&Wsh[(jj*16 + lr)*72 + k0 + kg*8];
      #pragma unroll
      for (int vt = 0; vt < 4; ++vt){
        half8 bX;
        #pragma unroll
        for (int j = 0; j < 8; ++j)
          bX[j] = Xsh[(k0 + kg*8 + j)*258 + w*64 + vt*16 + lr];
        #pragma unroll
        for (int jj = 0; jj < 4; ++jj)
          acc[vt][jj] = __builtin_amdgcn_mfma_f32_16x16x32_f16(aW[jj], bX, acc[vt][jj], 0, 0, 0);
      }
    }
  }

  size_t rowbase = ((size_t)b*58 + l)*64;
  #pragma unroll
  for (int jj = 0; jj < 4; ++jj){
    #pragma unroll
    for (int rr = 0; rr < 4; ++rr){
      int o = jj*16 + kg*4 + rr;
      float bv = Bsh[o];
      size_t obase = (rowbase + o)*512 + v0 + w*64 + lr;
      #pragma unroll
      for (int vt = 0; vt < 4; ++vt){
        float val = acc[vt][jj][rr] + bv;
        size_t addr = obase + vt*16;
        if (PASS == 0) tmp[addr] = (_Float16)val;
        else           tmp[addr] = (_Float16)((float)tmp[addr] + val);
      }
    }
  }
}

// ---------------- untranspose tmp[(b,l)][o][v] -> out[b][o][v][6+l], zero pad ----------------
__global__ __launch_bounds__(256) void untranspose(const _Float16* __restrict__ tmp,
                                                   float* __restrict__ out){
  __shared__ float T[58][65];
  int o = blockIdx.x;          // 64
  int b = blockIdx.y;          // 8
  int v0 = blockIdx.z * 64;    // 8
  int t = threadIdx.x;
  for (int idx = t; idx < 58*64; idx += 256){
    int lr = idx >> 6, vv = idx & 63;
    T[lr][vv] = (float)tmp[((size_t)(b*58 + lr)*64 + o)*NN + v0 + vv];
  }
  __syncthreads();
  #pragma unroll
  for (int i = 0; i < 16; ++i){
    int c = t + i*256;           // 0..4095
    int vv = c >> 6, tt = c & 63;
    float val = (tt < 6) ? 0.f : T[tt - 6][vv];
    out[((size_t)(b*64 + o)*NN + v0 + vv)*TT + tt] = val;
  }
}

// ---------------- launch ----------------
extern "C" void kernel_launch(void* const* d_in, const int* in_sizes, int n_in,
                              void* d_out, int out_size, void* d_ws, size_t ws_size,
                              hipStream_t stream){
  const float* x   = (const float*)d_in[0];
  const float* adj = (const float*)d_in[1];
  const float* w1[4] = {(const float*)d_in[2],  (const float*)d_in[4],
                        (const float*)d_in[6],  (const float*)d_in[8]};
  const float* b1[4] = {(const float*)d_in[3],  (const float*)d_in[5],
                        (const float*)d_in[7],  (const float*)d_in[9]};
  const float* w2[4] = {(const float*)d_in[10], (const float*)d_in[12],
                        (const float*)d_in[14], (const float*)d_in[16]};
  const float* b2[4] = {(const float*)d_in[11], (const float*)d_in[13],
                        (const float*)d_in[15], (const float*)d_in[17]};
  const float* m1w = (const float*)d_in[18];
  const float* m1b = (const float*)d_in[19];
  const float* m2w = (const float*)d_in[20];
  const float* m2b = (const float*)d_in[21];

  // workspace layout (bytes) — total ~185 MB
  char* wsb = (char*)d_ws;
  float* dinv1 = (float*)(wsb);
  float* dinv2 = (float*)(wsb + 2048);
  _Float16* U1  = (_Float16*)(wsb + 4096);             // 40 KB
  _Float16* U2  = (_Float16*)(wsb + 4096 + 40960);     // 40 KB
  _Float16* Mn  = (_Float16*)(wsb + 167936);           // M = An - I
  _Float16* MnT = (_Float16*)(wsb + 167936 + 524288);
  size_t sbytes = SZ * 2;
  char* sbase = wsb + 1216512;
  _Float16* S_h = (_Float16*)(sbase);                  // z0 = h
  _Float16* S2  = (_Float16*)(sbase + sbytes);         // z1
  _Float16* S3  = (_Float16*)(sbase + 2*sbytes);       // z2
  _Float16* S4  = (_Float16*)(sbase + 3*sbytes);       // z3
  _Float16* S5  = (_Float16*)(sbase + 4*sbytes);       // z4
  _Float16* tmp = (_Float16*)(sbase + 5*sbytes);
  _Float16* xTg = S2;   // dead before first gemm writes S2
  _Float16* WfG = (_Float16*)(sbase + 6*sbytes);        // 114688 B
  float* biasFG = (float*)(sbase + 6*sbytes + 114688);  // 512 B
  _Float16* M2  = (_Float16*)(sbase + 6*sbytes + 131072);           // 512 KB
  _Float16* MT2 = (_Float16*)(sbase + 6*sbytes + 131072 + 524288);  // 512 KB
  float* out = (float*)d_out;

  prep_adj<<<NN, 64, 0, stream>>>(adj, dinv1, dinv2);
  build_norm<<<NN, 256, 0, stream>>>(adj, dinv1, dinv2, Mn, MnT);
  // M2 = Mn^2 row-major = gemm(A=MnT,B=Mn); MT2 = MnT^2 row-major = gemm(A=Mn,B=MnT)
  gemm_z2<<<dim3(NN/64, 2, 2), 256, 0, stream>>>(MnT, Mn, M2, Mn, MnT, MT2);
  u_prep<<<80, 256, 0, stream>>>(m1w, m2w, U1, U2);
  wfg_prep<<<128, 448, 0, stream>>>(
      w1[0],w1[1],w1[2],w1[3], w2[0],w2[1],w2[2],w2[3],
      b1[0],b1[1],b1[2],b1[3], b2[0],b2[1],b2[2],b2[3], WfG, biasFG);
  xt_prep<<<dim3(NN, BB), 256, 0, stream>>>(x, xTg);
  inception_mfma<<<dim3(16, 9, 8), 256, 0, stream>>>(xTg, WfG, biasFG, S_h);

  dim3 gz(BCL/64, 2, 2);
  dim3 gc(2, LL, BB);
  for (int pass = 0; pass < 2; ++pass){
    const _Float16* Mp  = pass ? MnT : Mn;
    const _Float16* Mp2 = pass ? MT2 : M2;
    // z1 = Mp·h, z2 = Mp²·h   (independent)
    gemm_z2<<<gz, 256, 0, stream>>>(Mp, S_h, S2, Mp2, S_h, S3);
    // z3 = Mp²·z1, z4 = Mp²·z2 (independent)
    gemm_z2<<<gz, 256, 0, stream>>>(Mp2, S2, S4, Mp2, S3, S5);
    if (pass == 0)
      combine_mfma<0><<<gc, 256, 0, stream>>>(S_h, S2, S3, S4, S5, U1, m1b, tmp);
    else
      combine_mfma<1><<<gc, 256, 0, stream>>>(S_h, S2, S3, S4, S5, U2, m2b, tmp);
  }
  untranspose<<<dim3(64, 8, 8), 256, 0, stream>>>(tmp, out);
}

// Round 7
// 576.531 us; speedup vs baseline: 2.0172x; 1.0119x over previous
//
#include <hip/hip_runtime.h>
#include <math.h>

#define NN 512
#define BB 8
#define CC 64
#define TT 64
#define LL 58
#define CL (CC*LL)        // 3712
#define BCL (BB*CC*LL)    // 29696
#define SZ ((size_t)NN*BCL)   // 15,204,352 elements per state

typedef _Float16 half8 __attribute__((ext_vector_type(8)));
typedef _Float16 half4 __attribute__((ext_vector_type(4)));
typedef float f32x4 __attribute__((ext_vector_type(4)));

// ---------------- adjacency normalization ----------------
__global__ __launch_bounds__(64) void prep_adj(const float* __restrict__ adj,
                                               float* __restrict__ dinv1,
                                               float* __restrict__ dinv2){
  int v = blockIdx.x;
  int lane = threadIdx.x;
  float rs = 0.f, cs = 0.f;
  for (int w = lane; w < NN; w += 64){
    rs += adj[v*NN + w];
    cs += adj[w*NN + v];
  }
  for (int off = 32; off > 0; off >>= 1){
    rs += __shfl_down(rs, off);
    cs += __shfl_down(cs, off);
  }
  if (lane == 0){
    dinv1[v] = 1.f / sqrtf(rs + 1.f);
    dinv2[v] = 1.f / sqrtf(cs + 1.f);
  }
}

// emits M = D^-1/2(A+I)D^-1/2 - I  (f(y) = M·y since 0.5*ALPHA = 1, DT=1)
__global__ __launch_bounds__(256) void build_norm(const float* __restrict__ adj,
                                                  const float* __restrict__ dinv1,
                                                  const float* __restrict__ dinv2,
                                                  _Float16* __restrict__ An,
                                                  _Float16* __restrict__ AnT){
  int v = blockIdx.x;
  float d1v = dinv1[v], d2v = dinv2[v];
  for (int w = threadIdx.x; w < NN; w += 256){
    float diag = (v == w) ? 1.f : 0.f;
    An[v*NN + w]  = (_Float16)(d1v * (adj[v*NN + w] + diag) * dinv1[w] - diag);
    AnT[v*NN + w] = (_Float16)(d2v * (adj[w*NN + v] + diag) * dinv2[w] - diag);
  }
}

// ---------------- U prep: fold RK/concat coefficients into combine weights ----
__global__ __launch_bounds__(256) void u_prep(const float* __restrict__ W1,
                                              const float* __restrict__ W2,
                                              _Float16* __restrict__ U1,
                                              _Float16* __restrict__ U2){
  const float coef[5][5] = {
    {1.f, 1.f, 1.f, 1.f, 1.f},
    {0.f, 1.f/3.f, 2.f/3.f, 1.f, 1.f},
    {0.f, 0.f, 1.f/3.f, 1.f/3.f, 0.5f},
    {0.f, 0.f, 0.f, 1.f/3.f, 1.f/6.f},
    {0.f, 0.f, 0.f, 0.f, 1.f/24.f}};
  int idx = blockIdx.x*256 + threadIdx.x;   // grid 80 -> 20480
  int o = idx / 320, rem = idx - o*320;
  int d = rem >> 6, c = rem & 63;
  float a1 = 0.f, a2 = 0.f;
  #pragma unroll
  for (int s = 0; s < 5; ++s){
    float cf = coef[d][s];
    a1 += cf * W1[o*320 + s*64 + c];
    a2 += cf * W2[o*320 + s*64 + c];
  }
  U1[idx] = (_Float16)a1;
  U2[idx] = (_Float16)a2;
}

// ---------------- inception weight prep ----------------
__global__ __launch_bounds__(448) void wfg_prep(
    const float* __restrict__ w10, const float* __restrict__ w11,
    const float* __restrict__ w12, const float* __restrict__ w13,
    const float* __restrict__ w20, const float* __restrict__ w21,
    const float* __restrict__ w22, const float* __restrict__ w23,
    const float* __restrict__ b10, const float* __restrict__ b11,
    const float* __restrict__ b12, const float* __restrict__ b13,
    const float* __restrict__ b20, const float* __restrict__ b21,
    const float* __restrict__ b22, const float* __restrict__ b23,
    _Float16* __restrict__ WfG, float* __restrict__ biasFG){
  int r = blockIdx.x;         // 0..127
  int t = threadIdx.x;        // 0..447
  int qp = t >> 6, ic = t & 63;
  int gate = r >> 6;
  int j = (r >> 4) & 3;
  int oc = r & 15;
  const int kjs[4] = {2, 3, 6, 7};
  int kj = kjs[j];
  const float* wsel = gate ? ((j==0)?w20:(j==1)?w21:(j==2)?w22:w23)
                           : ((j==0)?w10:(j==1)?w11:(j==2)?w12:w13);
  int off = 7 - kj;
  float val = (qp >= off) ? wsel[(oc*64 + ic)*kj + (qp - off)] : 0.f;
  WfG[(size_t)r*448 + t] = (_Float16)val;
  if (t == 0){
    const float* bsel = gate ? ((j==0)?b20:(j==1)?b21:(j==2)?b22:b23)
                             : ((j==0)?b10:(j==1)?b11:(j==2)?b12:b13);
    biasFG[r] = bsel[oc];
  }
}

// ---------------- x transpose: x[b][ic][n][t] f32 -> xTg[b][t][n][ic] f16 ----------------
__global__ __launch_bounds__(256) void xt_prep(const float* __restrict__ x,
                                               _Float16* __restrict__ xTg){
  __shared__ float T[64][65];
  int n = blockIdx.x;   // 512
  int b = blockIdx.y;   // 8
  int tid = threadIdx.x;
  #pragma unroll
  for (int r = 0; r < 4; ++r){
    int f = tid + r*256;       // 0..1023
    int ic = f >> 4, t4 = f & 15;
    float4 v = *(const float4*)&x[(((size_t)(b*64 + ic))*512 + n)*64 + t4*4];
    T[ic][t4*4+0] = v.x; T[ic][t4*4+1] = v.y;
    T[ic][t4*4+2] = v.z; T[ic][t4*4+3] = v.w;
  }
  __syncthreads();
  #pragma unroll
  for (int r = 0; r < 2; ++r){
    int f = tid + r*256;       // 0..511
    int t = f >> 3, ch = f & 7;
    half8 hv;
    #pragma unroll
    for (int q2 = 0; q2 < 8; ++q2) hv[q2] = (_Float16)T[ch*8 + q2][t];
    *(half8*)&xTg[(((size_t)(b*64 + t))*512 + n)*64 + ch*8] = hv;
  }
}

// ---------------- inception via MFMA ----------------
__global__ __launch_bounds__(256, 3) void inception_mfma(
    const _Float16* __restrict__ xTg,   // [b][t][n][ic]
    const _Float16* __restrict__ WfG,   // [128][448]
    const float* __restrict__ biasFG,   // [128]
    _Float16* __restrict__ S_h){
  __shared__ _Float16 X[13*32*64];      // indexed in 8-half chunks
  int nt = blockIdx.x;   // 0..15
  int lt = blockIdx.y;   // 0..8
  int b  = blockIdx.z;   // 0..7
  int n0 = nt*32, l0 = lt*7;
  int tid = threadIdx.x;

  int sch = tid & 7, sn = (tid >> 3) & 31;
  #pragma unroll
  for (int r = 0; r < 13; ++r){
    int t = l0 + r;
    half8 v = {};
    if (t < 64)
      v = *(const half8*)&xTg[(((size_t)(b*64 + t))*512 + n0 + sn)*64 + sch*8];
    *(half8*)&X[(size_t)(r*256 + sn*8 + (sch ^ (sn & 7)))*8] = v;
  }

  int w = tid >> 6, lane = tid & 63;
  int m = lane & 15, kg = lane >> 4;

  half8 wF[14], wG[14];
  const _Float16* wb = WfG + (size_t)(w*16 + m)*448 + kg*8;
  #pragma unroll
  for (int s = 0; s < 14; ++s){
    wF[s] = *(const half8*)(wb + s*32);
    wG[s] = *(const half8*)(wb + (size_t)64*448 + s*32);
  }
  f32x4 bF = *(const f32x4*)&biasFG[w*16 + kg*4];
  f32x4 bG = *(const f32x4*)&biasFG[64 + w*16 + kg*4];

  __syncthreads();

  for (int ll = 0; ll < 7; ++ll){
    f32x4 aF0 = {}, aF1 = {}, aG0 = {}, aG1 = {};
    #pragma unroll
    for (int s = 0; s < 14; ++s){
      int t = ll + (s >> 1);
      int c0 = (s & 1)*4 + kg;
      half8 b0 = *(half8*)&X[(size_t)(t*256 + m*8        + (c0 ^ (m & 7)))*8];
      half8 b1 = *(half8*)&X[(size_t)(t*256 + (16+m)*8   + (c0 ^ (m & 7)))*8];
      aF0 = __builtin_amdgcn_mfma_f32_16x16x32_f16(wF[s], b0, aF0, 0, 0, 0);
      aG0 = __builtin_amdgcn_mfma_f32_16x16x32_f16(wG[s], b0, aG0, 0, 0, 0);
      aF1 = __builtin_amdgcn_mfma_f32_16x16x32_f16(wF[s], b1, aF1, 0, 0, 0);
      aG1 = __builtin_amdgcn_mfma_f32_16x16x32_f16(wG[s], b1, aG1, 0, 0, 0);
    }
    int l = l0 + ll;
    if (l < LL){
      #pragma unroll
      for (int rr = 0; rr < 4; ++rr){
        int c = w*16 + kg*4 + rr;
        float F0 = aF0[rr] + bF[rr];
        float G0 = aG0[rr] + bG[rr];
        float F1 = aF1[rr] + bF[rr];
        float G1 = aG1[rr] + bG[rr];
        float h0 = (2.f*__builtin_amdgcn_rcpf(1.f + __expf(-2.f*F0)) - 1.f)
                 * __builtin_amdgcn_rcpf(1.f + __expf(-G0));
        float h1 = (2.f*__builtin_amdgcn_rcpf(1.f + __expf(-2.f*F1)) - 1.f)
                 * __builtin_amdgcn_rcpf(1.f + __expf(-G1));
        size_t base = ((size_t)(b*64 + c)*LL + l)*NN + n0;
        S_h[base + m]      = (_Float16)h0;
        S_h[base + 16 + m] = (_Float16)h1;
      }
    }
  }
}

// ---------------- dual Krylov GEMM, rotate-swizzled LDS (conflict-free) ------
// LDS layout: chunk c of row r stored at r*32 + ((c + (r>>1))&3)*8 halfs.
// Bank quad Q=(4r+c') mod 8 -> any (lr 0..15, kg) frag access tiles all 8 quads
// 2-way (free); stores likewise. LDS = 20 KB.
__global__ __launch_bounds__(256) void gemm_z2(
    const _Float16* __restrict__ A0, const _Float16* __restrict__ B0,
    _Float16* __restrict__ O0,
    const _Float16* __restrict__ A1, const _Float16* __restrict__ B1,
    _Float16* __restrict__ O1){
  const _Float16* A  = blockIdx.z ? A1 : A0;
  const _Float16* Bst = blockIdx.z ? B1 : B0;
  _Float16* O = blockIdx.z ? O1 : O0;

  __shared__ _Float16 Ash[256*32];
  __shared__ _Float16 Bsh[64*32];
  int t = threadIdx.x;
  int m0 = blockIdx.x * 64;
  int v0 = blockIdx.y * 256;
  int w = t >> 6;
  int lane = t & 63;
  int lr = lane & 15;
  int kg = lane >> 4;

  // store-side swizzle (const across i since i*256 contributes 0 mod 4)
  int sr = t >> 2;                         // row within tile (i adds 64)
  int ssw = ((t & 3) + ((t >> 3) & 3)) & 3; // (sg + (r>>1)) & 3
  int saoff = sr*32 + ssw*8;               // + i*64*32
  // read-side swizzle: c' = (kg + (lr>>1)) & 3 (const across i/jj: rows step by 16)
  int cp = (kg + (lr >> 1)) & 3;
  int raoff0 = (w*64 + lr)*32 + cp*8;      // af[i] at + i*16*32
  int rboff0 = lr*32 + cp*8;               // bf[jj] at + jj*16*32

  f32x4 acc[4][4] = {};

  for (int k0 = 0; k0 < NN; k0 += 32){
    half8 areg[4];
    #pragma unroll
    for (int i = 0; i < 4; ++i)
      areg[i] = *(const half8*)&A[(size_t)(v0 + sr + i*64)*NN + k0 + (t & 3)*8];
    half8 breg = *(const half8*)&Bst[(size_t)(m0 + sr)*NN + k0 + (t & 3)*8];

    __syncthreads();
    #pragma unroll
    for (int i = 0; i < 4; ++i)
      *(half8*)&Ash[saoff + i*2048] = areg[i];
    *(half8*)&Bsh[saoff] = breg;
    __syncthreads();

    half8 af[4], bf[4];
    #pragma unroll
    for (int i = 0; i < 4; ++i) af[i] = *(half8*)&Ash[raoff0 + i*512];
    #pragma unroll
    for (int jj = 0; jj < 4; ++jj) bf[jj] = *(half8*)&Bsh[rboff0 + jj*512];
    #pragma unroll
    for (int i = 0; i < 4; ++i)
      #pragma unroll
      for (int jj = 0; jj < 4; ++jj)
        acc[i][jj] = __builtin_amdgcn_mfma_f32_16x16x32_f16(af[i], bf[jj], acc[i][jj], 0, 0, 0);
  }

  int q = lane >> 4;
  #pragma unroll
  for (int i = 0; i < 4; ++i){
    #pragma unroll
    for (int jj = 0; jj < 4; ++jj){
      int vv = v0 + w*64 + i*16 + q*4;
      int mq = m0 + jj*16 + lr;
      size_t base = (size_t)mq*NN + vv;
      half4 oq;
      #pragma unroll
      for (int rr = 0; rr < 4; ++rr)
        oq[rr] = (_Float16)acc[i][jj][rr];
      *(half4*)(O + base) = oq;
    }
  }
}

// ---------------- 1x1 mix via MFMA over Krylov basis ----------------
template<int PASS>
__global__ __launch_bounds__(256) void combine_mfma(
    const _Float16* __restrict__ Sh, const _Float16* __restrict__ S2,
    const _Float16* __restrict__ S3, const _Float16* __restrict__ S4,
    const _Float16* __restrict__ Sf,
    const _Float16* __restrict__ Wc,   // U_p [64][320] f16
    const float* __restrict__ bias,    // [64]
    _Float16* __restrict__ tmp){
  __shared__ _Float16 Xsh[64*258];
  __shared__ _Float16 Wsh[64*72];
  __shared__ float Bsh[64];
  int v0 = blockIdx.x * 256;
  int l  = blockIdx.y;
  int b  = blockIdx.z;
  int tid = threadIdx.x;
  int w = tid >> 6, lane = tid & 63;
  int lr = lane & 15, kg = lane >> 4;

  if (tid < 64) Bsh[tid] = bias[tid];

  const _Float16* Sarr[5] = {Sh, S2, S3, S4, Sf};
  f32x4 acc[4][4] = {};   // [vt][jj]

  for (int kt = 0; kt < 5; ++kt){
    const _Float16* S = Sarr[kt];
    __syncthreads();
    #pragma unroll
    for (int r = 0; r < 8; ++r){
      int f = tid + r*256;        // 0..2047
      int c = f >> 5, ch = f & 31;
      half8 xv = *(const half8*)&S[((size_t)(b*64 + c)*58 + l)*512 + v0 + ch*8];
      *(half8*)&Xsh[c*258 + ch*8] = xv;
    }
    #pragma unroll
    for (int r = 0; r < 2; ++r){
      int f = tid + r*256;        // 0..511
      int o = f >> 3, ch = f & 7;
      *(half8*)&Wsh[o*72 + ch*8] = *(const half8*)&Wc[(size_t)o*320 + kt*64 + ch*8];
    }
    __syncthreads();

    #pragma unroll
    for (int ks = 0; ks < 2; ++ks){
      int k0 = ks*32;
      half8 aW[4];
      #pragma unroll
      for (int jj = 0; jj < 4; ++jj)
        aW[jj] = *(half8*)&Wsh[(jj*16 + lr)*72 + k0 + kg*8];
      #pragma unroll
      for (int vt = 0; vt < 4; ++vt){
        half8 bX;
        #pragma unroll
        for (int j = 0; j < 8; ++j)
          bX[j] = Xsh[(k0 + kg*8 + j)*258 + w*64 + vt*16 + lr];
        #pragma unroll
        for (int jj = 0; jj < 4; ++jj)
          acc[vt][jj] = __builtin_amdgcn_mfma_f32_16x16x32_f16(aW[jj], bX, acc[vt][jj], 0, 0, 0);
      }
    }
  }

  size_t rowbase = ((size_t)b*58 + l)*64;
  #pragma unroll
  for (int jj = 0; jj < 4; ++jj){
    #pragma unroll
    for (int rr = 0; rr < 4; ++rr){
      int o = jj*16 + kg*4 + rr;
      float bv = Bsh[o];
      size_t obase = (rowbase + o)*512 + v0 + w*64 + lr;
      #pragma unroll
      for (int vt = 0; vt < 4; ++vt){
        float val = acc[vt][jj][rr] + bv;
        size_t addr = obase + vt*16;
        if (PASS == 0) tmp[addr] = (_Float16)val;
        else           tmp[addr] = (_Float16)((float)tmp[addr] + val);
      }
    }
  }
}

// ---------------- untranspose tmp[(b,l)][o][v] -> out[b][o][v][6+l], zero pad ----------------
__global__ __launch_bounds__(256) void untranspose(const _Float16* __restrict__ tmp,
                                                   float* __restrict__ out){
  __shared__ float T[58][65];
  int o = blockIdx.x;          // 64
  int b = blockIdx.y;          // 8
  int v0 = blockIdx.z * 64;    // 8
  int t = threadIdx.x;
  for (int idx = t; idx < 58*64; idx += 256){
    int lr = idx >> 6, vv = idx & 63;
    T[lr][vv] = (float)tmp[((size_t)(b*58 + lr)*64 + o)*NN + v0 + vv];
  }
  __syncthreads();
  #pragma unroll
  for (int i = 0; i < 16; ++i){
    int c = t + i*256;           // 0..4095
    int vv = c >> 6, tt = c & 63;
    float val = (tt < 6) ? 0.f : T[tt - 6][vv];
    out[((size_t)(b*64 + o)*NN + v0 + vv)*TT + tt] = val;
  }
}

// ---------------- launch ----------------
extern "C" void kernel_launch(void* const* d_in, const int* in_sizes, int n_in,
                              void* d_out, int out_size, void* d_ws, size_t ws_size,
                              hipStream_t stream){
  const float* x   = (const float*)d_in[0];
  const float* adj = (const float*)d_in[1];
  const float* w1[4] = {(const float*)d_in[2],  (const float*)d_in[4],
                        (const float*)d_in[6],  (const float*)d_in[8]};
  const float* b1[4] = {(const float*)d_in[3],  (const float*)d_in[5],
                        (const float*)d_in[7],  (const float*)d_in[9]};
  const float* w2[4] = {(const float*)d_in[10], (const float*)d_in[12],
                        (const float*)d_in[14], (const float*)d_in[16]};
  const float* b2[4] = {(const float*)d_in[11], (const float*)d_in[13],
                        (const float*)d_in[15], (const float*)d_in[17]};
  const float* m1w = (const float*)d_in[18];
  const float* m1b = (const float*)d_in[19];
  const float* m2w = (const float*)d_in[20];
  const float* m2b = (const float*)d_in[21];

  // workspace layout (bytes) — total ~185 MB
  char* wsb = (char*)d_ws;
  float* dinv1 = (float*)(wsb);
  float* dinv2 = (float*)(wsb + 2048);
  _Float16* U1  = (_Float16*)(wsb + 4096);             // 40 KB
  _Float16* U2  = (_Float16*)(wsb + 4096 + 40960);     // 40 KB
  _Float16* Mn  = (_Float16*)(wsb + 167936);           // M = An - I
  _Float16* MnT = (_Float16*)(wsb + 167936 + 524288);
  size_t sbytes = SZ * 2;
  char* sbase = wsb + 1216512;
  _Float16* S_h = (_Float16*)(sbase);                  // z0 = h
  _Float16* S2  = (_Float16*)(sbase + sbytes);         // z1
  _Float16* S3  = (_Float16*)(sbase + 2*sbytes);       // z2
  _Float16* S4  = (_Float16*)(sbase + 3*sbytes);       // z3
  _Float16* S5  = (_Float16*)(sbase + 4*sbytes);       // z4
  _Float16* tmp = (_Float16*)(sbase + 5*sbytes);
  _Float16* xTg = S2;   // dead before first gemm writes S2
  _Float16* WfG = (_Float16*)(sbase + 6*sbytes);        // 114688 B
  float* biasFG = (float*)(sbase + 6*sbytes + 114688);  // 512 B
  _Float16* M2  = (_Float16*)(sbase + 6*sbytes + 131072);           // 512 KB
  _Float16* MT2 = (_Float16*)(sbase + 6*sbytes + 131072 + 524288);  // 512 KB
  float* out = (float*)d_out;

  prep_adj<<<NN, 64, 0, stream>>>(adj, dinv1, dinv2);
  build_norm<<<NN, 256, 0, stream>>>(adj, dinv1, dinv2, Mn, MnT);
  // M2 = Mn^2 row-major = gemm(A=MnT,B=Mn); MT2 = MnT^2 row-major = gemm(A=Mn,B=MnT)
  gemm_z2<<<dim3(NN/64, 2, 2), 256, 0, stream>>>(MnT, Mn, M2, Mn, MnT, MT2);
  u_prep<<<80, 256, 0, stream>>>(m1w, m2w, U1, U2);
  wfg_prep<<<128, 448, 0, stream>>>(
      w1[0],w1[1],w1[2],w1[3], w2[0],w2[1],w2[2],w2[3],
      b1[0],b1[1],b1[2],b1[3], b2[0],b2[1],b2[2],b2[3], WfG, biasFG);
  xt_prep<<<dim3(NN, BB), 256, 0, stream>>>(x, xTg);
  inception_mfma<<<dim3(16, 9, 8), 256, 0, stream>>>(xTg, WfG, biasFG, S_h);

  dim3 gz(BCL/64, 2, 2);
  dim3 gc(2, LL, BB);
  for (int pass = 0; pass < 2; ++pass){
    const _Float16* Mp  = pass ? MnT : Mn;
    const _Float16* Mp2 = pass ? MT2 : M2;
    // z1 = Mp·h, z2 = Mp²·h   (independent)
    gemm_z2<<<gz, 256, 0, stream>>>(Mp, S_h, S2, Mp2, S_h, S3);
    // z3 = Mp²·z1, z4 = Mp²·z2 (independent)
    gemm_z2<<<gz, 256, 0, stream>>>(Mp2, S2, S4, Mp2, S3, S5);
    if (pass == 0)
      combine_mfma<0><<<gc, 256, 0, stream>>>(S_h, S2, S3, S4, S5, U1, m1b, tmp);
    else
      combine_mfma<1><<<gc, 256, 0, stream>>>(S_h, S2, S3, S4, S5, U2, m2b, tmp);
  }
  untranspose<<<dim3(64, 8, 8), 256, 0, stream>>>(tmp, out);
}